// Round 3
// baseline (69386.829 us; speedup 1.0000x reference)
//
#include <hip/hip_runtime.h>
#include <math.h>

#define Tn 256
#define Bn 64
#define Hn 512
#define CHUNK 64
#define EPSF 1e-15f
#define NBLK 256

__device__ __forceinline__ float artanh_f(float x){
  x = fminf(fmaxf(x, -1.0f + 1e-7f), 1.0f - 1e-7f);
  return 0.5f * (log1pf(x) - log1pf(-x));
}

template<int N>
__device__ __forceinline__ void block_reduceN(float* v, float* red){
  #pragma unroll
  for (int off = 32; off > 0; off >>= 1){
    #pragma unroll
    for (int n = 0; n < N; ++n) v[n] += __shfl_xor(v[n], off);
  }
  const int tid = threadIdx.x;
  const int w = tid >> 6;
  __syncthreads();
  if ((tid & 63) == 0){
    #pragma unroll
    for (int n = 0; n < N; ++n) red[n*4 + w] = v[n];
  }
  __syncthreads();
  #pragma unroll
  for (int n = 0; n < N; ++n)
    v[n] = red[n*4+0] + red[n*4+1] + red[n*4+2] + red[n*4+3];
}

// ---------------- device-scope grid barrier (all NBLK blocks co-resident) ---
__device__ __forceinline__ void grid_barrier(unsigned* cnt, unsigned target){
  __syncthreads();
  if (threadIdx.x == 0){
    __threadfence();   // release all prior global writes device-wide
    __hip_atomic_fetch_add(cnt, 1u, __ATOMIC_RELEASE, __HIP_MEMORY_SCOPE_AGENT);
    while (__hip_atomic_load(cnt, __ATOMIC_ACQUIRE, __HIP_MEMORY_SCOPE_AGENT) < target)
      __builtin_amdgcn_s_sleep(4);
    __threadfence();   // acquire side
  }
  __syncthreads();
}

// ---------------- precompute GEMM: C[r][c] = dot(A[r,:512], B[c,:512]) -------
#define GBM 64
#define GBN 64
#define GBK 16

__global__ __launch_bounds__(256) void gemm_tn(
    const float* __restrict__ A,   // M x 512 row-major (M = CHUNK*Bn)
    const float* __restrict__ Bm,  // 1536 x 512 row-major
    float* __restrict__ Cm)        // M x 1536
{
  __shared__ __align__(16) float As[GBK][GBM];
  __shared__ __align__(16) float Bs[GBK][GBN];
  const int tid = threadIdx.x;
  const int rm0 = blockIdx.x * GBM;
  const int cn0 = blockIdx.y * GBN;
  const int lr = tid >> 2;
  const int lk = (tid & 3) * 4;
  const int tx = tid & 15;
  const int ty = tid >> 4;
  float acc[4][4] = {};
  const float* Arow = A  + (size_t)(rm0 + lr) * 512 + lk;
  const float* Brow = Bm + (size_t)(cn0 + lr) * 512 + lk;
  for (int k0 = 0; k0 < 512; k0 += GBK){
    const float4 av = *reinterpret_cast<const float4*>(Arow + k0);
    const float4 bv = *reinterpret_cast<const float4*>(Brow + k0);
    __syncthreads();
    As[lk+0][lr]=av.x; As[lk+1][lr]=av.y; As[lk+2][lr]=av.z; As[lk+3][lr]=av.w;
    Bs[lk+0][lr]=bv.x; Bs[lk+1][lr]=bv.y; Bs[lk+2][lr]=bv.z; Bs[lk+3][lr]=bv.w;
    __syncthreads();
    #pragma unroll
    for (int kk = 0; kk < GBK; ++kk){
      const float4 a4 = *reinterpret_cast<const float4*>(&As[kk][tx*4]);
      const float4 b4 = *reinterpret_cast<const float4*>(&Bs[kk][ty*4]);
      const float ar[4] = {a4.x, a4.y, a4.z, a4.w};
      const float br[4] = {b4.x, b4.y, b4.z, b4.w};
      #pragma unroll
      for (int i = 0; i < 4; ++i)
        #pragma unroll
        for (int j = 0; j < 4; ++j)
          acc[i][j] = fmaf(ar[i], br[j], acc[i][j]);
    }
  }
  #pragma unroll
  for (int i = 0; i < 4; ++i){
    float4 st; st.x=acc[i][0]; st.y=acc[i][1]; st.z=acc[i][2]; st.w=acc[i][3];
    *reinterpret_cast<float4*>(&Cm[(size_t)(rm0 + tx*4 + i)*1536 + cn0 + ty*4]) = st;
  }
}

// ------- apply mobius_matvec scaling to P rows -------------------------------
__global__ __launch_bounds__(256) void scale_kernel(
    const float* __restrict__ src,  // nrows x 512 (layer input rows)
    float* __restrict__ P)          // nrows x 1536 (mx, scaled in place)
{
  __shared__ float red[24];
  const int row = blockIdx.x, tid = threadIdx.x;
  const float x0 = src[(size_t)row*512 + tid];
  const float x1 = src[(size_t)row*512 + tid + 256];
  float v[3];
  v[0] = x0*x0 + x1*x1; v[1] = 0.f; v[2] = 0.f;
  block_reduceN<3>(v, red);
  const float xn = sqrtf(v[0] + EPSF);
  const float artx = artanh_f(xn);
  float* Prow = P + (size_t)row*1536;
  float p[6];
  #pragma unroll
  for (int g = 0; g < 3; ++g){
    p[2*g]   = Prow[g*512 + tid];
    p[2*g+1] = Prow[g*512 + tid + 256];
  }
  float m[3];
  #pragma unroll
  for (int g = 0; g < 3; ++g) m[g] = p[2*g]*p[2*g] + p[2*g+1]*p[2*g+1];
  block_reduceN<3>(m, red);
  #pragma unroll
  for (int g = 0; g < 3; ++g){
    const float mn = sqrtf(m[g] + EPSF);
    const float s = tanhf(mn / xn * artx) / mn;
    Prow[g*512 + tid]       = s * p[2*g];
    Prow[g*512 + tid + 256] = s * p[2*g+1];
  }
}

// ---------------- persistent recurrence kernel -------------------------------
// 256 blocks x 256 threads, loops over nsteps timesteps; phases separated by
// grid_barrier. Phase work = direct ports of the round-2 kernels.
#define RT 16
#define BT 16

__global__ __launch_bounds__(256) void recur_kernel(
    const float* __restrict__ Whh,   // (1536,512): [r | hid | z]
    const float* __restrict__ bias,  // (3,512)
    const float* __restrict__ P,     // CHUNK*Bn x 1536 (scaled x-side)
    float* __restrict__ h,           // (B,512) in/out
    float* __restrict__ Mrz,         // (B,1024)
    float* __restrict__ Mh,          // (B,512)
    float* __restrict__ rhb,         // (B,512)
    float* __restrict__ zb,          // (B,512)
    float* __restrict__ outseq,      // (T,B,H)
    float* __restrict__ lastdst,     // (B,H) written at t==Tn-1
    unsigned* __restrict__ cnt,      // barrier counter (zeroed before launch)
    int t0, int nsteps)
{
  __shared__ __align__(16) float hs[BT][516];
  __shared__ float red[24];
  const int bid = blockIdx.x;
  const int tid = threadIdx.x;
  unsigned bar = 0;

  for (int tt = 0; tt < nsteps; ++tt){
    const int t = t0 + tt;
    const int tc = tt;

    // ---------------- phase 1: matvec rz (all 256 blocks) ----------------
    {
      const int rg = bid >> 2, bg = bid & 3;
      // stage h[bg*16 .. +16][512] into LDS
      for (int idx = tid*4; idx < BT*512; idx += 1024){
        const int r = idx >> 9, c = idx & 511;
        const float4 vv = *reinterpret_cast<const float4*>(&h[(size_t)(bg*BT + r)*512 + c]);
        *reinterpret_cast<float4*>(&hs[r][c]) = vv;
      }
      __syncthreads();
      const int i = tid >> 4, jb = tid & 15;
      const int gr = rg * RT + i;                 // 0..1023
      const int row = (gr < 512) ? gr : gr + 512; // r rows or z rows
      const float4* wp = reinterpret_cast<const float4*>(Whh + (size_t)row * 512);
      const float* hrow = hs[jb];
      float a0 = 0.f, a1 = 0.f, a2 = 0.f, a3 = 0.f;
      #pragma unroll 8
      for (int k = 0; k < 128; ++k){
        const float4 w = wp[k];
        const float4 x = *reinterpret_cast<const float4*>(&hrow[k*4]);
        a0 = fmaf(w.x, x.x, a0);
        a1 = fmaf(w.y, x.y, a1);
        a2 = fmaf(w.z, x.z, a2);
        a3 = fmaf(w.w, x.w, a3);
      }
      Mrz[(size_t)(bg*BT + jb) * 1024 + gr] = (a0 + a1) + (a2 + a3);
      __syncthreads();   // protect hs before next restage
    }
    grid_barrier(cnt, (++bar) * NBLK);

    // ---------------- phase 2: gates (blocks 0..127) ----------------------
    if (bid < 128){
      const int which = bid >> 6;   // 0 = r-chain (+rh), 1 = z-chain
      const int b = bid & 63;
      const int j0 = tid, j1 = tid + 256;
      const float h0 = h[(size_t)b*512 + j0], h1 = h[(size_t)b*512 + j1];
      const float* Prow = P + (size_t)(tc*Bn + b)*1536;
      float v[3];
      if (which == 0){
        const float m0 = Mrz[(size_t)b*1024 + j0], m1 = Mrz[(size_t)b*1024 + j1];
        v[0] = h0*h0 + h1*h1; v[1] = m0*m0 + m1*m1;
        block_reduceN<2>(v, red);
        const float hn2 = v[0];
        const float xn_h = sqrtf(hn2 + EPSF);
        const float artx_h = artanh_f(xn_h);
        const float mn = sqrtf(v[1] + EPSF);
        const float s = tanhf(mn / xn_h * artx_h) / mn;
        const float x2 = s*s*v[1];
        const float vv0 = s*m0, vv1 = s*m1;
        const float p0 = Prow[j0], p1 = Prow[j1];
        v[0] = p0*p0 + p1*p1; v[1] = vv0*p0 + vv1*p1;
        block_reduceN<2>(v, red);
        float na = 1.f + 2.f*v[1] + v[0];
        float nb = 1.f - x2;
        float den = fmaxf(1.f + 2.f*v[1] + x2*v[0], EPSF);
        const float q0 = (na*vv0 + nb*p0)/den, q1 = (na*vv1 + nb*p1)/den;
        const float bb0 = bias[j0], bb1 = bias[j1];
        v[0] = q0*q0 + q1*q1; v[1] = bb0*bb0 + bb1*bb1; v[2] = q0*bb0 + q1*bb1;
        block_reduceN<3>(v, red);
        na = 1.f + 2.f*v[2] + v[1];
        nb = 1.f - v[0];
        den = fmaxf(1.f + 2.f*v[2] + v[0]*v[1], EPSF);
        const float w0 = (na*q0 + nb*bb0)/den, w1 = (na*q1 + nb*bb1)/den;
        v[0] = w0*w0 + w1*w1;
        block_reduceN<1>(v, red);
        const float yn = sqrtf(v[0] + EPSF);
        const float sc = artanh_f(yn) / yn;
        const float r0 = 1.f/(1.f + expf(-sc*w0)), r1 = 1.f/(1.f + expf(-sc*w1));
        const float u0 = r0*h0, u1 = r1*h1;
        v[0] = u0*u0 + u1*u1;
        block_reduceN<1>(v, red);
        const float wn = sqrtf(v[0] + EPSF);
        const float s_rh = tanhf(wn / xn_h * artx_h) / wn;
        rhb[(size_t)b*512 + j0] = s_rh*u0;
        rhb[(size_t)b*512 + j1] = s_rh*u1;
      } else {
        const float m0 = Mrz[(size_t)b*1024 + 512 + j0], m1 = Mrz[(size_t)b*1024 + 512 + j1];
        v[0] = h0*h0 + h1*h1; v[1] = m0*m0 + m1*m1;
        block_reduceN<2>(v, red);
        const float hn2 = v[0];
        const float xn_h = sqrtf(hn2 + EPSF);
        const float artx_h = artanh_f(xn_h);
        const float mn = sqrtf(v[1] + EPSF);
        const float s = tanhf(mn / xn_h * artx_h) / mn;
        const float x2 = s*s*v[1];
        const float vv0 = s*m0, vv1 = s*m1;
        const float p0 = Prow[1024 + j0], p1 = Prow[1024 + j1];
        v[0] = p0*p0 + p1*p1; v[1] = vv0*p0 + vv1*p1;
        block_reduceN<2>(v, red);
        float na = 1.f + 2.f*v[1] + v[0];
        float nb = 1.f - x2;
        float den = fmaxf(1.f + 2.f*v[1] + x2*v[0], EPSF);
        const float q0 = (na*vv0 + nb*p0)/den, q1 = (na*vv1 + nb*p1)/den;
        const float bb0 = bias[1024 + j0], bb1 = bias[1024 + j1];
        v[0] = q0*q0 + q1*q1; v[1] = bb0*bb0 + bb1*bb1; v[2] = q0*bb0 + q1*bb1;
        block_reduceN<3>(v, red);
        na = 1.f + 2.f*v[2] + v[1];
        nb = 1.f - v[0];
        den = fmaxf(1.f + 2.f*v[2] + v[0]*v[1], EPSF);
        const float w0 = (na*q0 + nb*bb0)/den, w1 = (na*q1 + nb*bb1)/den;
        v[0] = w0*w0 + w1*w1;
        block_reduceN<1>(v, red);
        const float yn = sqrtf(v[0] + EPSF);
        const float sc = artanh_f(yn) / yn;
        zb[(size_t)b*512 + j0] = 1.f/(1.f + expf(-sc*w0));
        zb[(size_t)b*512 + j1] = 1.f/(1.f + expf(-sc*w1));
      }
    }
    grid_barrier(cnt, (++bar) * NBLK);

    // ---------------- phase 3: matvec h (blocks 0..127) -------------------
    if (bid < 128){
      const int rg = bid >> 2, bg = bid & 3;
      for (int idx = tid*4; idx < BT*512; idx += 1024){
        const int r = idx >> 9, c = idx & 511;
        const float4 vv = *reinterpret_cast<const float4*>(&rhb[(size_t)(bg*BT + r)*512 + c]);
        *reinterpret_cast<float4*>(&hs[r][c]) = vv;
      }
      __syncthreads();
      const int i = tid >> 4, jb = tid & 15;
      const int gr = rg * RT + i;                 // 0..511
      const float4* wp = reinterpret_cast<const float4*>(Whh + (size_t)(gr + 512) * 512);
      const float* hrow = hs[jb];
      float a0 = 0.f, a1 = 0.f, a2 = 0.f, a3 = 0.f;
      #pragma unroll 8
      for (int k = 0; k < 128; ++k){
        const float4 w = wp[k];
        const float4 x = *reinterpret_cast<const float4*>(&hrow[k*4]);
        a0 = fmaf(w.x, x.x, a0);
        a1 = fmaf(w.y, x.y, a1);
        a2 = fmaf(w.z, x.z, a2);
        a3 = fmaf(w.w, x.w, a3);
      }
      Mh[(size_t)(bg*BT + jb) * 512 + gr] = (a0 + a1) + (a2 + a3);
      __syncthreads();
    }
    grid_barrier(cnt, (++bar) * NBLK);

    // ---------------- phase 4: finish (blocks 0..63) ----------------------
    if (bid < 64){
      const int b = bid;
      const int j0 = tid, j1 = tid + 256;
      const float h0 = h[(size_t)b*512 + j0],  h1 = h[(size_t)b*512 + j1];
      const float rh0 = rhb[(size_t)b*512 + j0], rh1 = rhb[(size_t)b*512 + j1];
      const float m0 = Mh[(size_t)b*512 + j0],  m1 = Mh[(size_t)b*512 + j1];
      float v[3];
      v[0] = h0*h0 + h1*h1;
      v[1] = rh0*rh0 + rh1*rh1;
      v[2] = m0*m0 + m1*m1;
      block_reduceN<3>(v, red);
      const float hn2 = v[0];
      const float xn_rh = sqrtf(v[1] + EPSF);
      const float artx = artanh_f(xn_rh);
      const float mn2 = v[2];
      const float mn = sqrtf(mn2 + EPSF);
      const float s = tanhf(mn / xn_rh * artx) / mn;
      const float v0 = s*m0, v1s = s*m1;
      const float x2 = s*s*mn2;
      const float* Prow = P + (size_t)(tc*Bn + b)*1536 + 512;
      const float p0 = Prow[j0], p1 = Prow[j1];
      v[0] = p0*p0 + p1*p1;  v[1] = v0*p0 + v1s*p1;
      block_reduceN<2>(v, red);
      float na = 1.f + 2.f*v[1] + v[0];
      float nb = 1.f - x2;
      float den = fmaxf(1.f + 2.f*v[1] + x2*v[0], EPSF);
      const float q0 = (na*v0 + nb*p0)/den, q1 = (na*v1s + nb*p1)/den;
      const float bb0 = bias[512 + j0], bb1 = bias[512 + j1];
      v[0] = q0*q0 + q1*q1;  v[1] = bb0*bb0 + bb1*bb1;  v[2] = q0*bb0 + q1*bb1;
      block_reduceN<3>(v, red);
      na = 1.f + 2.f*v[2] + v[1];
      nb = 1.f - v[0];
      den = fmaxf(1.f + 2.f*v[2] + v[0]*v[1], EPSF);
      float ht0 = (na*q0 + nb*bb0)/den, ht1 = (na*q1 + nb*bb1)/den;
      v[0] = ht0*ht0 + ht1*ht1;  v[1] = h0*ht0 + h1*ht1;
      block_reduceN<2>(v, red);
      {
        const float y2 = v[0], xy = -v[1];
        na = 1.f + 2.f*xy + y2;
        nb = 1.f - hn2;
        den = fmaxf(1.f + 2.f*xy + hn2*y2, EPSF);
        const float d0 = (na*(-h0) + nb*ht0)/den;
        const float d1 = (na*(-h1) + nb*ht1)/den;
        ht0 = d0; ht1 = d1;
      }
      const float z0 = zb[(size_t)b*512 + j0], z1 = zb[(size_t)b*512 + j1];
      const float wz0 = z0*ht0, wz1 = z1*ht1;
      v[0] = ht0*ht0 + ht1*ht1;
      v[1] = wz0*wz0 + wz1*wz1;
      v[2] = h0*wz0 + h1*wz1;
      block_reduceN<3>(v, red);
      const float dn  = sqrtf(v[0] + EPSF);
      const float wzn = sqrtf(v[1] + EPSF);
      const float s_pw = tanhf(wzn / dn * artanh_f(dn)) / wzn;
      const float y2p = s_pw*s_pw*v[1];
      const float xyp = s_pw*v[2];
      na = 1.f + 2.f*xyp + y2p;
      nb = 1.f - hn2;
      den = fmaxf(1.f + 2.f*xyp + hn2*y2p, EPSF);
      const float hn0 = (na*h0 + nb*s_pw*wz0)/den;
      const float hn1 = (na*h1 + nb*s_pw*wz1)/den;
      h[(size_t)b*512 + j0] = hn0;
      h[(size_t)b*512 + j1] = hn1;
      outseq[((size_t)t*Bn + b)*512 + j0] = hn0;
      outseq[((size_t)t*Bn + b)*512 + j1] = hn1;
      if (t == Tn-1){
        lastdst[(size_t)b*512 + j0] = hn0;
        lastdst[(size_t)b*512 + j1] = hn1;
      }
    }
    grid_barrier(cnt, (++bar) * NBLK);
  }
}

extern "C" void kernel_launch(void* const* d_in, const int* in_sizes, int n_in,
                              void* d_out, int out_size, void* d_ws, size_t ws_size,
                              hipStream_t stream)
{
  const float* inp  = (const float*)d_in[0];   // (T,B,H)
  const float* Wih  = (const float*)d_in[1];   // (L,3H,H)
  const float* Whh  = (const float*)d_in[2];   // (L,3H,H)
  const float* bias = (const float*)d_in[3];   // (L,3,H)
  float* out  = (float*)d_out;                 // (T,B,H)
  float* last = out + (size_t)Tn*Bn*Hn;        // (L,B,H)

  float*    P    = (float*)d_ws;                    // CHUNK*Bn x 1536
  float*    hbuf = P + (size_t)CHUNK*Bn*1536;       // Bn x 512
  float*    Mrz  = hbuf + (size_t)Bn*512;           // Bn x 1024
  float*    Mh   = Mrz + (size_t)Bn*1024;           // Bn x 512
  float*    rhb  = Mh + (size_t)Bn*512;             // Bn x 512
  float*    zbuf = rhb + (size_t)Bn*512;            // Bn x 512
  unsigned* cnt  = (unsigned*)(zbuf + (size_t)Bn*512);

  for (int l = 0; l < 2; ++l){
    const float* src   = (l == 0) ? inp : out;
    const float* Wihl  = Wih  + (size_t)l*1536*Hn;
    const float* Whhl  = Whh  + (size_t)l*1536*Hn;
    const float* biasl = bias + (size_t)l*3*Hn;
    hipMemsetAsync(hbuf, 0, (size_t)Bn*512*sizeof(float), stream);
    for (int c = 0; c < Tn/CHUNK; ++c){
      const float* srcc = src + (size_t)c*CHUNK*Bn*Hn;
      dim3 gg(CHUNK*Bn/GBM, 1536/GBN);
      hipLaunchKernelGGL(gemm_tn, gg, dim3(256), 0, stream, srcc, Wihl, P);
      hipLaunchKernelGGL(scale_kernel, dim3(CHUNK*Bn), dim3(256), 0, stream,
                         srcc, P);
      hipMemsetAsync(cnt, 0, sizeof(unsigned), stream);
      hipLaunchKernelGGL(recur_kernel, dim3(NBLK), dim3(256), 0, stream,
                         Whhl, biasl, P, hbuf, Mrz, Mh, rhb, zbuf,
                         out, last + (size_t)l*Bn*Hn, cnt,
                         c*CHUNK, CHUNK);
    }
  }
}

// Round 4
// 28570.694 us; speedup vs baseline: 2.4286x; 2.4286x over previous
//
#include <hip/hip_runtime.h>
#include <math.h>

#define Tn 256
#define Bn 64
#define Hn 512
#define CHUNK 64
#define EPSF 1e-15f
#define GPB 64     // blocks per barrier group
#define NGRP 4     // groups (64 blocks, 16 batches each)
#define NB 16      // batches per group
#define HPAD 516   // LDS row stride (floats): conflict-free float4 reads
#define FSTRIDE 32 // flag stride (uints) = 128B, one line per block

__device__ __forceinline__ float artanh_f(float x){
  x = fminf(fmaxf(x, -1.0f + 1e-7f), 1.0f - 1e-7f);
  return 0.5f * (log1pf(x) - log1pf(-x));
}

__device__ __forceinline__ float red16(float v){
  v += __shfl_xor(v, 1);
  v += __shfl_xor(v, 2);
  v += __shfl_xor(v, 4);
  v += __shfl_xor(v, 8);
  return v;
}

// contention-free group barrier: per-block flag stores + read-only polling
__device__ __forceinline__ void gbar(unsigned* gflags, int bl, unsigned ep){
  __syncthreads();                       // drains vmcnt: block's stores done
  if (threadIdx.x == 0){
    __threadfence();                     // publish device-wide
    __hip_atomic_store(gflags + (size_t)bl*FSTRIDE, ep,
                       __ATOMIC_RELEASE, __HIP_MEMORY_SCOPE_AGENT);
  }
  if (threadIdx.x < GPB){
    while (__hip_atomic_load(gflags + (size_t)threadIdx.x*FSTRIDE,
                             __ATOMIC_ACQUIRE, __HIP_MEMORY_SCOPE_AGENT) < ep) {}
  }
  __syncthreads();
}

template<int N>
__device__ __forceinline__ void block_reduceN(float* v, float* red){
  #pragma unroll
  for (int off = 32; off > 0; off >>= 1){
    #pragma unroll
    for (int n = 0; n < N; ++n) v[n] += __shfl_xor(v[n], off);
  }
  const int tid = threadIdx.x;
  const int w = tid >> 6;
  __syncthreads();
  if ((tid & 63) == 0){
    #pragma unroll
    for (int n = 0; n < N; ++n) red[n*4 + w] = v[n];
  }
  __syncthreads();
  #pragma unroll
  for (int n = 0; n < N; ++n)
    v[n] = red[n*4+0] + red[n*4+1] + red[n*4+2] + red[n*4+3];
}

// ---------------- precompute GEMM: C[r][c] = dot(A[r,:512], B[c,:512]) -------
#define GBM 64
#define GBN 64
#define GBK 16

__global__ __launch_bounds__(256) void gemm_tn(
    const float* __restrict__ A,   // M x 512 row-major (M = CHUNK*Bn)
    const float* __restrict__ Bm,  // 1536 x 512 row-major
    float* __restrict__ Cm)        // M x 1536
{
  __shared__ __align__(16) float As[GBK][GBM];
  __shared__ __align__(16) float Bs[GBK][GBN];
  const int tid = threadIdx.x;
  const int rm0 = blockIdx.x * GBM;
  const int cn0 = blockIdx.y * GBN;
  const int lr = tid >> 2;
  const int lk = (tid & 3) * 4;
  const int tx = tid & 15;
  const int ty = tid >> 4;
  float acc[4][4] = {};
  const float* Arow = A  + (size_t)(rm0 + lr) * 512 + lk;
  const float* Brow = Bm + (size_t)(cn0 + lr) * 512 + lk;
  for (int k0 = 0; k0 < 512; k0 += GBK){
    const float4 av = *reinterpret_cast<const float4*>(Arow + k0);
    const float4 bv = *reinterpret_cast<const float4*>(Brow + k0);
    __syncthreads();
    As[lk+0][lr]=av.x; As[lk+1][lr]=av.y; As[lk+2][lr]=av.z; As[lk+3][lr]=av.w;
    Bs[lk+0][lr]=bv.x; Bs[lk+1][lr]=bv.y; Bs[lk+2][lr]=bv.z; Bs[lk+3][lr]=bv.w;
    __syncthreads();
    #pragma unroll
    for (int kk = 0; kk < GBK; ++kk){
      const float4 a4 = *reinterpret_cast<const float4*>(&As[kk][tx*4]);
      const float4 b4 = *reinterpret_cast<const float4*>(&Bs[kk][ty*4]);
      const float ar[4] = {a4.x, a4.y, a4.z, a4.w};
      const float br[4] = {b4.x, b4.y, b4.z, b4.w};
      #pragma unroll
      for (int i = 0; i < 4; ++i)
        #pragma unroll
        for (int j = 0; j < 4; ++j)
          acc[i][j] = fmaf(ar[i], br[j], acc[i][j]);
    }
  }
  #pragma unroll
  for (int i = 0; i < 4; ++i){
    float4 st; st.x=acc[i][0]; st.y=acc[i][1]; st.z=acc[i][2]; st.w=acc[i][3];
    *reinterpret_cast<float4*>(&Cm[(size_t)(rm0 + tx*4 + i)*1536 + cn0 + ty*4]) = st;
  }
}

// ------- apply mobius_matvec scaling to P rows -------------------------------
__global__ __launch_bounds__(256) void scale_kernel(
    const float* __restrict__ src,  // nrows x 512 (layer input rows)
    float* __restrict__ P)          // nrows x 1536 (mx, scaled in place)
{
  __shared__ float red[24];
  const int row = blockIdx.x, tid = threadIdx.x;
  const float x0 = src[(size_t)row*512 + tid];
  const float x1 = src[(size_t)row*512 + tid + 256];
  float v[3];
  v[0] = x0*x0 + x1*x1; v[1] = 0.f; v[2] = 0.f;
  block_reduceN<3>(v, red);
  const float xn = sqrtf(v[0] + EPSF);
  const float artx = artanh_f(xn);
  float* Prow = P + (size_t)row*1536;
  float p[6];
  #pragma unroll
  for (int g = 0; g < 3; ++g){
    p[2*g]   = Prow[g*512 + tid];
    p[2*g+1] = Prow[g*512 + tid + 256];
  }
  float m[3];
  #pragma unroll
  for (int g = 0; g < 3; ++g) m[g] = p[2*g]*p[2*g] + p[2*g+1]*p[2*g+1];
  block_reduceN<3>(m, red);
  #pragma unroll
  for (int g = 0; g < 3; ++g){
    const float mn = sqrtf(m[g] + EPSF);
    const float s = tanhf(mn / xn * artx) / mn;
    Prow[g*512 + tid]       = s * p[2*g];
    Prow[g*512 + tid + 256] = s * p[2*g+1];
  }
}

// ---------------- persistent recurrence: 4 groups x 64 blocks ----------------
// per step: A(mv_rz) | bar | B(r-chain + mv_hid) | bar | C(z-chain + finish)
// chains vectorized across batches: 16 lanes per batch, shfl_xor reduces.
__global__ __launch_bounds__(256) void recur_kernel(
    const float* __restrict__ Whh,   // (1536,512): [r | hid | z]
    const float* __restrict__ bias,  // (3,512): [b_r, b_h, b_z]
    const float* __restrict__ P,     // CHUNK*Bn x 1536 (scaled x-side)
    const float* __restrict__ hinit, // (B,512) previous h, or nullptr -> zeros
    float* __restrict__ Mrz,         // [2][Bn][1024] double-buffered
    float* __restrict__ Mh,          // [Bn][512]
    float* __restrict__ outseq,      // (T,B,H)
    float* __restrict__ lastdst,     // (B,H), written at t==Tn-1
    unsigned* __restrict__ flags,    // NGRP * GPB * FSTRIDE, zeroed
    int t0, int nsteps)
{
  __shared__ __align__(16) float h_lds[NB][HPAD];
  __shared__ __align__(16) float v_lds[NB][HPAD];   // rh in B, z in C
  __shared__ float stats[NB][4];                    // xn_rh, artx_rh, hn2
  const int bid = blockIdx.x, tid = threadIdx.x;
  const int g = bid >> 6, bl = bid & 63;
  unsigned* gflags = flags + (size_t)g * GPB * FSTRIDE;
  unsigned ep = 0;
  const int bb = tid >> 4;   // chain batch (0..15)
  const int l  = tid & 15;   // chain lane

  for (int idx = tid; idx < NB*512; idx += 256){
    const int b2 = idx >> 9, j = idx & 511;
    h_lds[b2][j] = hinit ? hinit[(size_t)(g*NB + b2)*512 + j] : 0.f;
  }
  __syncthreads();

  for (int tt = 0; tt < nsteps; ++tt){
    const int t = t0 + tt;
    const int buf = tt & 1;

    // ---------------- A: mv_rz ----------------
    {
      const int bm = tid & 15;              // batch
      const int row_local = bl*16 + (tid >> 4);   // 0..1023
      const int wrow = (row_local < 512) ? row_local : row_local + 512;
      const float4* wp = reinterpret_cast<const float4*>(Whh + (size_t)wrow * 512);
      const float* hv = h_lds[bm];
      float a0=0.f,a1=0.f,a2=0.f,a3=0.f;
      #pragma unroll 8
      for (int k = 0; k < 128; ++k){
        const float4 w = wp[k];
        const float4 x = *reinterpret_cast<const float4*>(&hv[4*k]);
        a0=fmaf(w.x,x.x,a0); a1=fmaf(w.y,x.y,a1);
        a2=fmaf(w.z,x.z,a2); a3=fmaf(w.w,x.w,a3);
      }
      Mrz[((size_t)buf*Bn + g*NB + bm)*1024 + row_local] = (a0+a1)+(a2+a3);
    }
    gbar(gflags, bl, ++ep);

    // ---------------- B: r-chain (all threads) + mv_hid ----------------
    {
      const int b = g*NB + bb;
      const float* Mr = Mrz + ((size_t)buf*Bn + b)*1024;
      const float* pr = P + ((size_t)tt*Bn + b)*1536;
      float m[32], p[32], bv[32], h[32];
      #pragma unroll
      for (int k = 0; k < 32; ++k){
        const int j = l + 16*k;
        m[k] = Mr[j]; p[k] = pr[j]; bv[k] = bias[j]; h[k] = h_lds[bb][j];
      }
      float hn2p=0.f, m2p=0.f;
      #pragma unroll
      for (int k = 0; k < 32; ++k){ hn2p=fmaf(h[k],h[k],hn2p); m2p=fmaf(m[k],m[k],m2p); }
      const float hn2 = red16(hn2p);
      const float m2  = red16(m2p);
      const float xn_h = sqrtf(hn2 + EPSF);
      const float artx_h = artanh_f(xn_h);
      const float mn = sqrtf(m2 + EPSF);
      const float s = tanhf(mn/xn_h*artx_h)/mn;
      const float x2 = s*s*m2;
      float y2p=0.f, xyp=0.f;
      #pragma unroll
      for (int k = 0; k < 32; ++k){ y2p=fmaf(p[k],p[k],y2p); xyp=fmaf(s*m[k],p[k],xyp); }
      const float y2 = red16(y2p), xy = red16(xyp);
      float na = 1.f + 2.f*xy + y2;
      float nb = 1.f - x2;
      float den = fmaxf(1.f + 2.f*xy + x2*y2, EPSF);
      #pragma unroll
      for (int k = 0; k < 32; ++k) p[k] = (na*s*m[k] + nb*p[k])/den;   // p := q
      float q2p=0.f, b2p=0.f, qbp=0.f;
      #pragma unroll
      for (int k = 0; k < 32; ++k){
        q2p=fmaf(p[k],p[k],q2p); b2p=fmaf(bv[k],bv[k],b2p); qbp=fmaf(p[k],bv[k],qbp);
      }
      const float q2 = red16(q2p), b2v = red16(b2p), qb = red16(qbp);
      na = 1.f + 2.f*qb + b2v;
      nb = 1.f - q2;
      den = fmaxf(1.f + 2.f*qb + q2*b2v, EPSF);
      float w2p = 0.f;
      #pragma unroll
      for (int k = 0; k < 32; ++k){
        m[k] = (na*p[k] + nb*bv[k])/den;                               // m := w
        w2p = fmaf(m[k], m[k], w2p);
      }
      const float w2 = red16(w2p);
      const float yn = sqrtf(w2 + EPSF);
      const float sc = artanh_f(yn)/yn;
      float u2p = 0.f;
      #pragma unroll
      for (int k = 0; k < 32; ++k){
        const float r = 1.f/(1.f + expf(-sc*m[k]));
        m[k] = r*h[k];                                                 // m := u
        u2p = fmaf(m[k], m[k], u2p);
      }
      const float u2 = red16(u2p);
      const float wn = sqrtf(u2 + EPSF);
      const float s_rh = tanhf(wn/xn_h*artx_h)/wn;
      #pragma unroll
      for (int k = 0; k < 32; ++k) v_lds[bb][l + 16*k] = s_rh*m[k];    // rh
      if (l == 0){
        const float xnrh = sqrtf(s_rh*s_rh*u2 + EPSF);
        stats[bb][0] = xnrh;
        stats[bb][1] = artanh_f(xnrh);
        stats[bb][2] = hn2;
      }
    }
    __syncthreads();
    if (tid < 128){   // mv_hid
      const int rr = tid >> 4, bm = tid & 15;
      const int wrow = 512 + bl*8 + rr;
      const float4* wp = reinterpret_cast<const float4*>(Whh + (size_t)wrow*512);
      const float* hv = v_lds[bm];
      float a0=0.f,a1=0.f,a2=0.f,a3=0.f;
      #pragma unroll 8
      for (int k = 0; k < 128; ++k){
        const float4 w = wp[k];
        const float4 x = *reinterpret_cast<const float4*>(&hv[4*k]);
        a0=fmaf(w.x,x.x,a0); a1=fmaf(w.y,x.y,a1);
        a2=fmaf(w.z,x.z,a2); a3=fmaf(w.w,x.w,a3);
      }
      Mh[(size_t)(g*NB + bm)*512 + bl*8 + rr] = (a0+a1)+(a2+a3);
    }
    gbar(gflags, bl, ++ep);

    // ---------------- C: z-chain + finish ----------------
    {
      const int b = g*NB + bb;
      const float* prow = P + ((size_t)tt*Bn + b)*1536;
      const float hn2 = stats[bb][2];
      const float xn_h = sqrtf(hn2 + EPSF);
      const float artx_h = artanh_f(xn_h);
      // ---- z-chain ----
      {
        const float* Mz = Mrz + ((size_t)buf*Bn + b)*1024 + 512;
        float m[32], p[32], bv[32];
        #pragma unroll
        for (int k = 0; k < 32; ++k){
          const int j = l + 16*k;
          m[k] = Mz[j]; p[k] = prow[1024 + j]; bv[k] = bias[1024 + j];
        }
        float m2p = 0.f;
        #pragma unroll
        for (int k = 0; k < 32; ++k) m2p = fmaf(m[k],m[k],m2p);
        const float m2 = red16(m2p);
        const float mn = sqrtf(m2 + EPSF);
        const float s = tanhf(mn/xn_h*artx_h)/mn;
        const float x2 = s*s*m2;
        float y2p=0.f, xyp=0.f;
        #pragma unroll
        for (int k = 0; k < 32; ++k){ y2p=fmaf(p[k],p[k],y2p); xyp=fmaf(s*m[k],p[k],xyp); }
        const float y2 = red16(y2p), xy = red16(xyp);
        float na = 1.f + 2.f*xy + y2;
        float nb = 1.f - x2;
        float den = fmaxf(1.f + 2.f*xy + x2*y2, EPSF);
        #pragma unroll
        for (int k = 0; k < 32; ++k) p[k] = (na*s*m[k] + nb*p[k])/den;  // q
        float q2p=0.f, b2p=0.f, qbp=0.f;
        #pragma unroll
        for (int k = 0; k < 32; ++k){
          q2p=fmaf(p[k],p[k],q2p); b2p=fmaf(bv[k],bv[k],b2p); qbp=fmaf(p[k],bv[k],qbp);
        }
        const float q2 = red16(q2p), b2v = red16(b2p), qb = red16(qbp);
        na = 1.f + 2.f*qb + b2v;
        nb = 1.f - q2;
        den = fmaxf(1.f + 2.f*qb + q2*b2v, EPSF);
        float w2p = 0.f;
        #pragma unroll
        for (int k = 0; k < 32; ++k){
          m[k] = (na*p[k] + nb*bv[k])/den;                              // w
          w2p = fmaf(m[k], m[k], w2p);
        }
        const float w2 = red16(w2p);
        const float yn = sqrtf(w2 + EPSF);
        const float sc = artanh_f(yn)/yn;
        #pragma unroll
        for (int k = 0; k < 32; ++k)
          v_lds[bb][l + 16*k] = 1.f/(1.f + expf(-sc*m[k]));             // z
      }
      // ---- finish ----
      {
        const float xn_rh = stats[bb][0];
        const float artx_rh = stats[bb][1];
        float m[32], p[32], bv[32], h[32];
        #pragma unroll
        for (int k = 0; k < 32; ++k){
          const int j = l + 16*k;
          m[k] = Mh[(size_t)b*512 + j];
          p[k] = prow[512 + j];
          bv[k] = bias[512 + j];
          h[k] = h_lds[bb][j];
        }
        float m2p = 0.f;
        #pragma unroll
        for (int k = 0; k < 32; ++k) m2p = fmaf(m[k],m[k],m2p);
        const float m2 = red16(m2p);
        const float mn = sqrtf(m2 + EPSF);
        const float s = tanhf(mn/xn_rh*artx_rh)/mn;
        const float x2 = s*s*m2;
        float y2p=0.f, xyp=0.f;
        #pragma unroll
        for (int k = 0; k < 32; ++k){ y2p=fmaf(p[k],p[k],y2p); xyp=fmaf(s*m[k],p[k],xyp); }
        const float y2 = red16(y2p), xy = red16(xyp);
        float na = 1.f + 2.f*xy + y2;
        float nb = 1.f - x2;
        float den = fmaxf(1.f + 2.f*xy + x2*y2, EPSF);
        #pragma unroll
        for (int k = 0; k < 32; ++k) p[k] = (na*s*m[k] + nb*p[k])/den;  // q
        float q2p=0.f, b2p=0.f, qbp=0.f;
        #pragma unroll
        for (int k = 0; k < 32; ++k){
          q2p=fmaf(p[k],p[k],q2p); b2p=fmaf(bv[k],bv[k],b2p); qbp=fmaf(p[k],bv[k],qbp);
        }
        const float q2 = red16(q2p), b2v = red16(b2p), qb = red16(qbp);
        na = 1.f + 2.f*qb + b2v;
        nb = 1.f - q2;
        den = fmaxf(1.f + 2.f*qb + q2*b2v, EPSF);
        #pragma unroll
        for (int k = 0; k < 32; ++k) m[k] = (na*p[k] + nb*bv[k])/den;   // ht
        // delta = mobius_add(-h, ht)
        float ht2p=0.f, hhtp=0.f;
        #pragma unroll
        for (int k = 0; k < 32; ++k){ ht2p=fmaf(m[k],m[k],ht2p); hhtp=fmaf(h[k],m[k],hhtp); }
        const float hty2 = red16(ht2p), hht = red16(hhtp);
        na = 1.f - 2.f*hht + hty2;
        nb = 1.f - hn2;
        den = fmaxf(1.f - 2.f*hht + hn2*hty2, EPSF);
        #pragma unroll
        for (int k = 0; k < 32; ++k) p[k] = (na*(-h[k]) + nb*m[k])/den; // delta
        // wz = z * delta; reduces
        float dn2p=0.f, wzn2p=0.f, hwzp=0.f;
        #pragma unroll
        for (int k = 0; k < 32; ++k){
          bv[k] = v_lds[bb][l + 16*k] * p[k];                           // wz
          dn2p = fmaf(p[k], p[k], dn2p);
          wzn2p = fmaf(bv[k], bv[k], wzn2p);
          hwzp = fmaf(h[k], bv[k], hwzp);
        }
        const float dn2 = red16(dn2p), wzn2 = red16(wzn2p), hwz = red16(hwzp);
        const float dn = sqrtf(dn2 + EPSF);
        const float wzn = sqrtf(wzn2 + EPSF);
        const float s_pw = tanhf(wzn/dn*artanh_f(dn))/wzn;
        const float y2f = s_pw*s_pw*wzn2;
        const float xyf = s_pw*hwz;
        na = 1.f + 2.f*xyf + y2f;
        nb = 1.f - hn2;
        den = fmaxf(1.f + 2.f*xyf + hn2*y2f, EPSF);
        #pragma unroll
        for (int k = 0; k < 32; ++k)
          h_lds[bb][l + 16*k] = (na*h[k] + nb*s_pw*bv[k])/den;          // h_new
      }
    }
    __syncthreads();

    // write outseq: block bl writes quarter (bl>>4) of batch (bl&15)
    {
      const int bm = bl & 15;
      const int b = g*NB + bm;
      const int j0 = (bl >> 4)*128;
      if (tid < 128){
        const float vv = h_lds[bm][j0 + tid];
        outseq[((size_t)t*Bn + b)*512 + j0 + tid] = vv;
        if (t == Tn-1) lastdst[(size_t)b*512 + j0 + tid] = vv;
      }
    }
    // no grid barrier needed: next A reads only block-local h_lds;
    // Mrz WAR is handled by double-buffering (buf flips each step).
  }
}

extern "C" void kernel_launch(void* const* d_in, const int* in_sizes, int n_in,
                              void* d_out, int out_size, void* d_ws, size_t ws_size,
                              hipStream_t stream)
{
  const float* inp  = (const float*)d_in[0];   // (T,B,H)
  const float* Wih  = (const float*)d_in[1];   // (L,3H,H)
  const float* Whh  = (const float*)d_in[2];   // (L,3H,H)
  const float* bias = (const float*)d_in[3];   // (L,3,H)
  float* out  = (float*)d_out;                 // (T,B,H)
  float* last = out + (size_t)Tn*Bn*Hn;        // (L,B,H)

  float*    P     = (float*)d_ws;                       // CHUNK*Bn x 1536
  float*    Mrz   = P + (size_t)CHUNK*Bn*1536;          // 2 x Bn x 1024
  float*    Mh    = Mrz + (size_t)2*Bn*1024;            // Bn x 512
  unsigned* flags = (unsigned*)(Mh + (size_t)Bn*512);   // NGRP*GPB*FSTRIDE

  for (int l = 0; l < 2; ++l){
    const float* src   = (l == 0) ? inp : out;
    const float* Wihl  = Wih  + (size_t)l*1536*Hn;
    const float* Whhl  = Whh  + (size_t)l*1536*Hn;
    const float* biasl = bias + (size_t)l*3*Hn;
    for (int c = 0; c < Tn/CHUNK; ++c){
      const int t0 = c*CHUNK;
      const float* srcc = src + (size_t)t0*Bn*Hn;
      dim3 gg(CHUNK*Bn/GBM, 1536/GBN);
      hipLaunchKernelGGL(gemm_tn, gg, dim3(256), 0, stream, srcc, Wihl, P);
      hipLaunchKernelGGL(scale_kernel, dim3(CHUNK*Bn), dim3(256), 0, stream,
                         srcc, P);
      hipMemsetAsync(flags, 0, (size_t)NGRP*GPB*FSTRIDE*sizeof(unsigned), stream);
      const float* hinit = (t0 == 0) ? nullptr
                                     : out + ((size_t)(t0-1))*Bn*Hn;
      hipLaunchKernelGGL(recur_kernel, dim3(NGRP*GPB), dim3(256), 0, stream,
                         Whhl, biasl, P, hinit, Mrz, Mh,
                         out, last + (size_t)l*Bn*Hn, flags, t0, CHUNK);
    }
  }
}

// Round 5
// 18118.399 us; speedup vs baseline: 3.8296x; 1.5769x over previous
//
#include <hip/hip_runtime.h>
#include <math.h>

#define Tn 256
#define Bn 64
#define Hn 512
#define CHUNK 64
#define EPSF 1e-15f
#define GPB 64     // blocks per barrier group
#define NGRP 4     // groups (64 blocks, 16 batches each)
#define NB 16      // batches per group
#define HPAD 516   // LDS row stride (floats)
#define FSTRIDE 32 // flag stride (uints) = 128B, one line per block

__device__ __forceinline__ float artanh_f(float x){
  x = fminf(fmaxf(x, -1.0f + 1e-7f), 1.0f - 1e-7f);
  return 0.5f * (log1pf(x) - log1pf(-x));
}

__device__ __forceinline__ float red16(float v){
  v += __shfl_xor(v, 1);
  v += __shfl_xor(v, 2);
  v += __shfl_xor(v, 4);
  v += __shfl_xor(v, 8);
  return v;
}

// Coherent-point accesses for cross-block payloads: relaxed agent atomics
// compile to sc0/sc1 loads/stores (bypass stale L1/XCD-L2, served at the
// coherence point) WITHOUT any cache-invalidate instructions.
__device__ __forceinline__ void cstore_f(float* p, float v){
  __hip_atomic_store(p, v, __ATOMIC_RELAXED, __HIP_MEMORY_SCOPE_AGENT);
}
__device__ __forceinline__ float cload_f(const float* p){
  return __hip_atomic_load(p, __ATOMIC_RELAXED, __HIP_MEMORY_SCOPE_AGENT);
}

// Group barrier with NO acquire anywhere (acquire => buffer_inv => L2 nuke).
// __syncthreads drains each thread's vmcnt (compiler emits waitcnt before
// s_barrier), so all data stores are complete at the coherence point before
// the flag store. RELEASE on the flag adds writeback-only insurance.
__device__ __forceinline__ void gbar(unsigned* gflags, int bl, unsigned ep){
  __syncthreads();
  if (threadIdx.x == 0){
    __hip_atomic_store(gflags + (size_t)bl*FSTRIDE, ep,
                       __ATOMIC_RELEASE, __HIP_MEMORY_SCOPE_AGENT);
  }
  if (threadIdx.x < GPB){
    while (__hip_atomic_load(gflags + (size_t)threadIdx.x*FSTRIDE,
                             __ATOMIC_RELAXED, __HIP_MEMORY_SCOPE_AGENT) < ep)
      __builtin_amdgcn_s_sleep(1);
  }
  __syncthreads();
}

template<int N>
__device__ __forceinline__ void block_reduceN(float* v, float* red){
  #pragma unroll
  for (int off = 32; off > 0; off >>= 1){
    #pragma unroll
    for (int n = 0; n < N; ++n) v[n] += __shfl_xor(v[n], off);
  }
  const int tid = threadIdx.x;
  const int w = tid >> 6;
  __syncthreads();
  if ((tid & 63) == 0){
    #pragma unroll
    for (int n = 0; n < N; ++n) red[n*4 + w] = v[n];
  }
  __syncthreads();
  #pragma unroll
  for (int n = 0; n < N; ++n)
    v[n] = red[n*4+0] + red[n*4+1] + red[n*4+2] + red[n*4+3];
}

// ---------------- precompute GEMM: C[r][c] = dot(A[r,:512], B[c,:512]) -------
#define GBM 64
#define GBN 64
#define GBK 16

__global__ __launch_bounds__(256) void gemm_tn(
    const float* __restrict__ A,   // M x 512 row-major (M = CHUNK*Bn)
    const float* __restrict__ Bm,  // 1536 x 512 row-major
    float* __restrict__ Cm)        // M x 1536
{
  __shared__ __align__(16) float As[GBK][GBM];
  __shared__ __align__(16) float Bs[GBK][GBN];
  const int tid = threadIdx.x;
  const int rm0 = blockIdx.x * GBM;
  const int cn0 = blockIdx.y * GBN;
  const int lr = tid >> 2;
  const int lk = (tid & 3) * 4;
  const int tx = tid & 15;
  const int ty = tid >> 4;
  float acc[4][4] = {};
  const float* Arow = A  + (size_t)(rm0 + lr) * 512 + lk;
  const float* Brow = Bm + (size_t)(cn0 + lr) * 512 + lk;
  for (int k0 = 0; k0 < 512; k0 += GBK){
    const float4 av = *reinterpret_cast<const float4*>(Arow + k0);
    const float4 bv = *reinterpret_cast<const float4*>(Brow + k0);
    __syncthreads();
    As[lk+0][lr]=av.x; As[lk+1][lr]=av.y; As[lk+2][lr]=av.z; As[lk+3][lr]=av.w;
    Bs[lk+0][lr]=bv.x; Bs[lk+1][lr]=bv.y; Bs[lk+2][lr]=bv.z; Bs[lk+3][lr]=bv.w;
    __syncthreads();
    #pragma unroll
    for (int kk = 0; kk < GBK; ++kk){
      const float4 a4 = *reinterpret_cast<const float4*>(&As[kk][tx*4]);
      const float4 b4 = *reinterpret_cast<const float4*>(&Bs[kk][ty*4]);
      const float ar[4] = {a4.x, a4.y, a4.z, a4.w};
      const float br[4] = {b4.x, b4.y, b4.z, b4.w};
      #pragma unroll
      for (int i = 0; i < 4; ++i)
        #pragma unroll
        for (int j = 0; j < 4; ++j)
          acc[i][j] = fmaf(ar[i], br[j], acc[i][j]);
    }
  }
  #pragma unroll
  for (int i = 0; i < 4; ++i){
    float4 st; st.x=acc[i][0]; st.y=acc[i][1]; st.z=acc[i][2]; st.w=acc[i][3];
    *reinterpret_cast<float4*>(&Cm[(size_t)(rm0 + tx*4 + i)*1536 + cn0 + ty*4]) = st;
  }
}

// ------- apply mobius_matvec scaling to P rows -------------------------------
__global__ __launch_bounds__(256) void scale_kernel(
    const float* __restrict__ src,  // nrows x 512 (layer input rows)
    float* __restrict__ P)          // nrows x 1536 (mx, scaled in place)
{
  __shared__ float red[24];
  const int row = blockIdx.x, tid = threadIdx.x;
  const float x0 = src[(size_t)row*512 + tid];
  const float x1 = src[(size_t)row*512 + tid + 256];
  float v[3];
  v[0] = x0*x0 + x1*x1; v[1] = 0.f; v[2] = 0.f;
  block_reduceN<3>(v, red);
  const float xn = sqrtf(v[0] + EPSF);
  const float artx = artanh_f(xn);
  float* Prow = P + (size_t)row*1536;
  float p[6];
  #pragma unroll
  for (int g = 0; g < 3; ++g){
    p[2*g]   = Prow[g*512 + tid];
    p[2*g+1] = Prow[g*512 + tid + 256];
  }
  float m[3];
  #pragma unroll
  for (int g = 0; g < 3; ++g) m[g] = p[2*g]*p[2*g] + p[2*g+1]*p[2*g+1];
  block_reduceN<3>(m, red);
  #pragma unroll
  for (int g = 0; g < 3; ++g){
    const float mn = sqrtf(m[g] + EPSF);
    const float s = tanhf(mn / xn * artx) / mn;
    Prow[g*512 + tid]       = s * p[2*g];
    Prow[g*512 + tid + 256] = s * p[2*g+1];
  }
}

// ---------------- persistent recurrence: 4 groups x 64 blocks ----------------
// per step: A(mv_rz) | bar | B(r-chain + mv_hid) | bar | C(z-chain + finish)
// chains vectorized across batches: 16 lanes per batch, shfl_xor reduces.
__global__ __launch_bounds__(256) void recur_kernel(
    const float* __restrict__ Whh,   // (1536,512): [r | hid | z]
    const float* __restrict__ bias,  // (3,512): [b_r, b_h, b_z]
    const float* __restrict__ P,     // CHUNK*Bn x 1536 (scaled x-side)
    const float* __restrict__ hinit, // (B,512) previous h, or nullptr -> zeros
    float* __restrict__ Mrz,         // [2][Bn][1024] double-buffered
    float* __restrict__ Mh,          // [Bn][512]
    float* __restrict__ outseq,      // (T,B,H)
    float* __restrict__ lastdst,     // (B,H), written at t==Tn-1
    unsigned* __restrict__ flags,    // NGRP * GPB * FSTRIDE, zeroed
    int t0, int nsteps)
{
  __shared__ __align__(16) float h_lds[NB][HPAD];
  __shared__ __align__(16) float v_lds[NB][HPAD];   // rh in B, z in C
  __shared__ float stats[NB][4];                    // xn_rh, artx_rh, hn2
  const int bid = blockIdx.x, tid = threadIdx.x;
  const int g = bid >> 6, bl = bid & 63;
  unsigned* gflags = flags + (size_t)g * GPB * FSTRIDE;
  unsigned ep = 0;
  const int bb = tid >> 4;   // chain batch (0..15)
  const int l  = tid & 15;   // chain lane

  for (int idx = tid; idx < NB*512; idx += 256){
    const int b2 = idx >> 9, j = idx & 511;
    h_lds[b2][j] = hinit ? hinit[(size_t)(g*NB + b2)*512 + j] : 0.f;
  }
  __syncthreads();

  for (int tt = 0; tt < nsteps; ++tt){
    const int t = t0 + tt;
    const int buf = tt & 1;

    // ---------------- A: mv_rz ----------------
    {
      const int bm = tid & 15;              // batch
      const int row_local = bl*16 + (tid >> 4);   // 0..1023
      const int wrow = (row_local < 512) ? row_local : row_local + 512;
      const float4* wp = reinterpret_cast<const float4*>(Whh + (size_t)wrow * 512);
      const float* hv = h_lds[bm];
      float a0=0.f,a1=0.f,a2=0.f,a3=0.f;
      #pragma unroll 8
      for (int k = 0; k < 128; ++k){
        const float4 w = wp[k];
        const float4 x = *reinterpret_cast<const float4*>(&hv[4*k]);
        a0=fmaf(w.x,x.x,a0); a1=fmaf(w.y,x.y,a1);
        a2=fmaf(w.z,x.z,a2); a3=fmaf(w.w,x.w,a3);
      }
      cstore_f(&Mrz[((size_t)buf*Bn + g*NB + bm)*1024 + row_local],
               (a0+a1)+(a2+a3));
    }
    gbar(gflags, bl, ++ep);

    // ---------------- B: r-chain (all threads) + mv_hid ----------------
    {
      const int b = g*NB + bb;
      const float* Mr = Mrz + ((size_t)buf*Bn + b)*1024;
      const float* pr = P + ((size_t)tt*Bn + b)*1536;
      float m[32], p[32], bv[32], h[32];
      #pragma unroll
      for (int k = 0; k < 32; ++k){
        const int j = l + 16*k;
        m[k] = cload_f(Mr + j); p[k] = pr[j]; bv[k] = bias[j]; h[k] = h_lds[bb][j];
      }
      float hn2p=0.f, m2p=0.f;
      #pragma unroll
      for (int k = 0; k < 32; ++k){ hn2p=fmaf(h[k],h[k],hn2p); m2p=fmaf(m[k],m[k],m2p); }
      const float hn2 = red16(hn2p);
      const float m2  = red16(m2p);
      const float xn_h = sqrtf(hn2 + EPSF);
      const float artx_h = artanh_f(xn_h);
      const float mn = sqrtf(m2 + EPSF);
      const float s = tanhf(mn/xn_h*artx_h)/mn;
      const float x2 = s*s*m2;
      float y2p=0.f, xyp=0.f;
      #pragma unroll
      for (int k = 0; k < 32; ++k){ y2p=fmaf(p[k],p[k],y2p); xyp=fmaf(s*m[k],p[k],xyp); }
      const float y2 = red16(y2p), xy = red16(xyp);
      float na = 1.f + 2.f*xy + y2;
      float nb = 1.f - x2;
      float den = fmaxf(1.f + 2.f*xy + x2*y2, EPSF);
      #pragma unroll
      for (int k = 0; k < 32; ++k) p[k] = (na*s*m[k] + nb*p[k])/den;   // p := q
      float q2p=0.f, b2p=0.f, qbp=0.f;
      #pragma unroll
      for (int k = 0; k < 32; ++k){
        q2p=fmaf(p[k],p[k],q2p); b2p=fmaf(bv[k],bv[k],b2p); qbp=fmaf(p[k],bv[k],qbp);
      }
      const float q2 = red16(q2p), b2v = red16(b2p), qb = red16(qbp);
      na = 1.f + 2.f*qb + b2v;
      nb = 1.f - q2;
      den = fmaxf(1.f + 2.f*qb + q2*b2v, EPSF);
      float w2p = 0.f;
      #pragma unroll
      for (int k = 0; k < 32; ++k){
        m[k] = (na*p[k] + nb*bv[k])/den;                               // m := w
        w2p = fmaf(m[k], m[k], w2p);
      }
      const float w2 = red16(w2p);
      const float yn = sqrtf(w2 + EPSF);
      const float sc = artanh_f(yn)/yn;
      float u2p = 0.f;
      #pragma unroll
      for (int k = 0; k < 32; ++k){
        const float r = 1.f/(1.f + expf(-sc*m[k]));
        m[k] = r*h[k];                                                 // m := u
        u2p = fmaf(m[k], m[k], u2p);
      }
      const float u2 = red16(u2p);
      const float wn = sqrtf(u2 + EPSF);
      const float s_rh = tanhf(wn/xn_h*artx_h)/wn;
      #pragma unroll
      for (int k = 0; k < 32; ++k) v_lds[bb][l + 16*k] = s_rh*m[k];    // rh
      if (l == 0){
        const float xnrh = sqrtf(s_rh*s_rh*u2 + EPSF);
        stats[bb][0] = xnrh;
        stats[bb][1] = artanh_f(xnrh);
        stats[bb][2] = hn2;
      }
    }
    __syncthreads();
    if (tid < 128){   // mv_hid
      const int rr = tid >> 4, bm = tid & 15;
      const int wrow = 512 + bl*8 + rr;
      const float4* wp = reinterpret_cast<const float4*>(Whh + (size_t)wrow*512);
      const float* hv = v_lds[bm];
      float a0=0.f,a1=0.f,a2=0.f,a3=0.f;
      #pragma unroll 8
      for (int k = 0; k < 128; ++k){
        const float4 w = wp[k];
        const float4 x = *reinterpret_cast<const float4*>(&hv[4*k]);
        a0=fmaf(w.x,x.x,a0); a1=fmaf(w.y,x.y,a1);
        a2=fmaf(w.z,x.z,a2); a3=fmaf(w.w,x.w,a3);
      }
      cstore_f(&Mh[(size_t)(g*NB + bm)*512 + bl*8 + rr], (a0+a1)+(a2+a3));
    }
    gbar(gflags, bl, ++ep);

    // ---------------- C: z-chain + finish ----------------
    {
      const int b = g*NB + bb;
      const float* prow = P + ((size_t)tt*Bn + b)*1536;
      const float hn2 = stats[bb][2];
      const float xn_h = sqrtf(hn2 + EPSF);
      const float artx_h = artanh_f(xn_h);
      // ---- z-chain ----
      {
        const float* Mz = Mrz + ((size_t)buf*Bn + b)*1024 + 512;
        float m[32], p[32], bv[32];
        #pragma unroll
        for (int k = 0; k < 32; ++k){
          const int j = l + 16*k;
          m[k] = cload_f(Mz + j); p[k] = prow[1024 + j]; bv[k] = bias[1024 + j];
        }
        float m2p = 0.f;
        #pragma unroll
        for (int k = 0; k < 32; ++k) m2p = fmaf(m[k],m[k],m2p);
        const float m2 = red16(m2p);
        const float mn = sqrtf(m2 + EPSF);
        const float s = tanhf(mn/xn_h*artx_h)/mn;
        const float x2 = s*s*m2;
        float y2p=0.f, xyp=0.f;
        #pragma unroll
        for (int k = 0; k < 32; ++k){ y2p=fmaf(p[k],p[k],y2p); xyp=fmaf(s*m[k],p[k],xyp); }
        const float y2 = red16(y2p), xy = red16(xyp);
        float na = 1.f + 2.f*xy + y2;
        float nb = 1.f - x2;
        float den = fmaxf(1.f + 2.f*xy + x2*y2, EPSF);
        #pragma unroll
        for (int k = 0; k < 32; ++k) p[k] = (na*s*m[k] + nb*p[k])/den;  // q
        float q2p=0.f, b2p=0.f, qbp=0.f;
        #pragma unroll
        for (int k = 0; k < 32; ++k){
          q2p=fmaf(p[k],p[k],q2p); b2p=fmaf(bv[k],bv[k],b2p); qbp=fmaf(p[k],bv[k],qbp);
        }
        const float q2 = red16(q2p), b2v = red16(b2p), qb = red16(qbp);
        na = 1.f + 2.f*qb + b2v;
        nb = 1.f - q2;
        den = fmaxf(1.f + 2.f*qb + q2*b2v, EPSF);
        float w2p = 0.f;
        #pragma unroll
        for (int k = 0; k < 32; ++k){
          m[k] = (na*p[k] + nb*bv[k])/den;                              // w
          w2p = fmaf(m[k], m[k], w2p);
        }
        const float w2 = red16(w2p);
        const float yn = sqrtf(w2 + EPSF);
        const float sc = artanh_f(yn)/yn;
        #pragma unroll
        for (int k = 0; k < 32; ++k)
          v_lds[bb][l + 16*k] = 1.f/(1.f + expf(-sc*m[k]));             // z
      }
      // ---- finish ----
      {
        const float xn_rh = stats[bb][0];
        const float artx_rh = stats[bb][1];
        float m[32], p[32], bv[32], h[32];
        #pragma unroll
        for (int k = 0; k < 32; ++k){
          const int j = l + 16*k;
          m[k] = cload_f(&Mh[(size_t)b*512 + j]);
          p[k] = prow[512 + j];
          bv[k] = bias[512 + j];
          h[k] = h_lds[bb][j];
        }
        float m2p = 0.f;
        #pragma unroll
        for (int k = 0; k < 32; ++k) m2p = fmaf(m[k],m[k],m2p);
        const float m2 = red16(m2p);
        const float mn = sqrtf(m2 + EPSF);
        const float s = tanhf(mn/xn_rh*artx_rh)/mn;
        const float x2 = s*s*m2;
        float y2p=0.f, xyp=0.f;
        #pragma unroll
        for (int k = 0; k < 32; ++k){ y2p=fmaf(p[k],p[k],y2p); xyp=fmaf(s*m[k],p[k],xyp); }
        const float y2 = red16(y2p), xy = red16(xyp);
        float na = 1.f + 2.f*xy + y2;
        float nb = 1.f - x2;
        float den = fmaxf(1.f + 2.f*xy + x2*y2, EPSF);
        #pragma unroll
        for (int k = 0; k < 32; ++k) p[k] = (na*s*m[k] + nb*p[k])/den;  // q
        float q2p=0.f, b2p=0.f, qbp=0.f;
        #pragma unroll
        for (int k = 0; k < 32; ++k){
          q2p=fmaf(p[k],p[k],q2p); b2p=fmaf(bv[k],bv[k],b2p); qbp=fmaf(p[k],bv[k],qbp);
        }
        const float q2 = red16(q2p), b2v = red16(b2p), qb = red16(qbp);
        na = 1.f + 2.f*qb + b2v;
        nb = 1.f - q2;
        den = fmaxf(1.f + 2.f*qb + q2*b2v, EPSF);
        #pragma unroll
        for (int k = 0; k < 32; ++k) m[k] = (na*p[k] + nb*bv[k])/den;   // ht
        // delta = mobius_add(-h, ht)
        float ht2p=0.f, hhtp=0.f;
        #pragma unroll
        for (int k = 0; k < 32; ++k){ ht2p=fmaf(m[k],m[k],ht2p); hhtp=fmaf(h[k],m[k],hhtp); }
        const float hty2 = red16(ht2p), hht = red16(hhtp);
        na = 1.f - 2.f*hht + hty2;
        nb = 1.f - hn2;
        den = fmaxf(1.f - 2.f*hht + hn2*hty2, EPSF);
        #pragma unroll
        for (int k = 0; k < 32; ++k) p[k] = (na*(-h[k]) + nb*m[k])/den; // delta
        // wz = z * delta; reduces
        float dn2p=0.f, wzn2p=0.f, hwzp=0.f;
        #pragma unroll
        for (int k = 0; k < 32; ++k){
          bv[k] = v_lds[bb][l + 16*k] * p[k];                           // wz
          dn2p = fmaf(p[k], p[k], dn2p);
          wzn2p = fmaf(bv[k], bv[k], wzn2p);
          hwzp = fmaf(h[k], bv[k], hwzp);
        }
        const float dn2 = red16(dn2p), wzn2 = red16(wzn2p), hwz = red16(hwzp);
        const float dn = sqrtf(dn2 + EPSF);
        const float wzn = sqrtf(wzn2 + EPSF);
        const float s_pw = tanhf(wzn/dn*artanh_f(dn))/wzn;
        const float y2f = s_pw*s_pw*wzn2;
        const float xyf = s_pw*hwz;
        na = 1.f + 2.f*xyf + y2f;
        nb = 1.f - hn2;
        den = fmaxf(1.f + 2.f*xyf + hn2*y2f, EPSF);
        #pragma unroll
        for (int k = 0; k < 32; ++k)
          h_lds[bb][l + 16*k] = (na*h[k] + nb*s_pw*bv[k])/den;          // h_new
      }
    }
    __syncthreads();

    // write outseq: block bl writes quarter (bl>>4) of batch (bl&15)
    {
      const int bm = bl & 15;
      const int b = g*NB + bm;
      const int j0 = (bl >> 4)*128;
      if (tid < 128){
        const float vv = h_lds[bm][j0 + tid];
        outseq[((size_t)t*Bn + b)*512 + j0 + tid] = vv;
        if (t == Tn-1) lastdst[(size_t)b*512 + j0 + tid] = vv;
      }
    }
    // no grid barrier needed: next A reads only block-local h_lds;
    // Mrz WAR is handled by double-buffering (buf flips each step).
  }
}

extern "C" void kernel_launch(void* const* d_in, const int* in_sizes, int n_in,
                              void* d_out, int out_size, void* d_ws, size_t ws_size,
                              hipStream_t stream)
{
  const float* inp  = (const float*)d_in[0];   // (T,B,H)
  const float* Wih  = (const float*)d_in[1];   // (L,3H,H)
  const float* Whh  = (const float*)d_in[2];   // (L,3H,H)
  const float* bias = (const float*)d_in[3];   // (L,3,H)
  float* out  = (float*)d_out;                 // (T,B,H)
  float* last = out + (size_t)Tn*Bn*Hn;        // (L,B,H)

  float*    P     = (float*)d_ws;                       // CHUNK*Bn x 1536
  float*    Mrz   = P + (size_t)CHUNK*Bn*1536;          // 2 x Bn x 1024
  float*    Mh    = Mrz + (size_t)2*Bn*1024;            // Bn x 512
  unsigned* flags = (unsigned*)(Mh + (size_t)Bn*512);   // NGRP*GPB*FSTRIDE

  for (int l = 0; l < 2; ++l){
    const float* src   = (l == 0) ? inp : out;
    const float* Wihl  = Wih  + (size_t)l*1536*Hn;
    const float* Whhl  = Whh  + (size_t)l*1536*Hn;
    const float* biasl = bias + (size_t)l*3*Hn;
    for (int c = 0; c < Tn/CHUNK; ++c){
      const int t0 = c*CHUNK;
      const float* srcc = src + (size_t)t0*Bn*Hn;
      dim3 gg(CHUNK*Bn/GBM, 1536/GBN);
      hipLaunchKernelGGL(gemm_tn, gg, dim3(256), 0, stream, srcc, Wihl, P);
      hipLaunchKernelGGL(scale_kernel, dim3(CHUNK*Bn), dim3(256), 0, stream,
                         srcc, P);
      hipMemsetAsync(flags, 0, (size_t)NGRP*GPB*FSTRIDE*sizeof(unsigned), stream);
      const float* hinit = (t0 == 0) ? nullptr
                                     : out + ((size_t)(t0-1))*Bn*Hn;
      hipLaunchKernelGGL(recur_kernel, dim3(NGRP*GPB), dim3(256), 0, stream,
                         Whhl, biasl, P, hinit, Mrz, Mh,
                         out, last + (size_t)l*Bn*Hn, flags, t0, CHUNK);
    }
  }
}

// Round 6
// 11182.745 us; speedup vs baseline: 6.2048x; 1.6202x over previous
//
#include <hip/hip_runtime.h>
#include <math.h>

#define Tn 256
#define Bn 64
#define Hn 512
#define CHUNK 64
#define EPSF 1e-15f
#define NGRP 16     // independent barrier groups
#define GPB 16      // blocks per group
#define NBATCH 4    // batches per group (1 wave per batch in chain phases)
#define HPAD 516    // LDS row stride: breaks 4-way bank aliasing in matvec
#define FSTRIDE 32  // flag stride (uints) = 128B

__device__ __forceinline__ float artanh_f(float x){
  x = fminf(fmaxf(x, -1.0f + 1e-7f), 1.0f - 1e-7f);
  return 0.5f * (log1pf(x) - log1pf(-x));
}

// full-wave butterfly reduce of N values; every lane ends with the total.
template<int N>
__device__ __forceinline__ void red64N(float* v){
  #pragma unroll
  for (int off = 1; off < 64; off <<= 1){
    #pragma unroll
    for (int n = 0; n < N; ++n) v[n] += __shfl_xor(v[n], off);
  }
}

// Cross-block payloads: relaxed agent atomics (sc-flagged, write-through to
// the coherence point). NO release/acquire anywhere in the hot loop -> no
// buffer_wbl2 / buffer_inv -> weights stay resident in each XCD's L2.
__device__ __forceinline__ void cstore_f(float* p, float v){
  __hip_atomic_store(p, v, __ATOMIC_RELAXED, __HIP_MEMORY_SCOPE_AGENT);
}
__device__ __forceinline__ float cload_f(const float* p){
  return __hip_atomic_load(p, __ATOMIC_RELAXED, __HIP_MEMORY_SCOPE_AGENT);
}

// Group barrier: __syncthreads drains each wave's vmcnt before s_barrier, so
// all sc1 data stores are complete at the coherence point before tid0's
// RELAXED flag store. Readers poll relaxed. Zero cache-maintenance ops.
__device__ __forceinline__ void gbar(unsigned* gflags, int bl, unsigned ep){
  __syncthreads();
  if (threadIdx.x == 0){
    __hip_atomic_store(gflags + (size_t)bl*FSTRIDE, ep,
                       __ATOMIC_RELAXED, __HIP_MEMORY_SCOPE_AGENT);
  }
  if (threadIdx.x < GPB){
    while (__hip_atomic_load(gflags + (size_t)threadIdx.x*FSTRIDE,
                             __ATOMIC_RELAXED, __HIP_MEMORY_SCOPE_AGENT) < ep)
      __builtin_amdgcn_s_sleep(1);
  }
  __syncthreads();
}

template<int N>
__device__ __forceinline__ void block_reduceN(float* v, float* red){
  #pragma unroll
  for (int off = 32; off > 0; off >>= 1){
    #pragma unroll
    for (int n = 0; n < N; ++n) v[n] += __shfl_xor(v[n], off);
  }
  const int tid = threadIdx.x;
  const int w = tid >> 6;
  __syncthreads();
  if ((tid & 63) == 0){
    #pragma unroll
    for (int n = 0; n < N; ++n) red[n*4 + w] = v[n];
  }
  __syncthreads();
  #pragma unroll
  for (int n = 0; n < N; ++n)
    v[n] = red[n*4+0] + red[n*4+1] + red[n*4+2] + red[n*4+3];
}

// ---------------- precompute GEMM: C[r][c] = dot(A[r,:512], B[c,:512]) -------
#define GBM 64
#define GBN 64
#define GBK 16

__global__ __launch_bounds__(256) void gemm_tn(
    const float* __restrict__ A,   // M x 512 row-major (M = CHUNK*Bn)
    const float* __restrict__ Bm,  // 1536 x 512 row-major
    float* __restrict__ Cm)        // M x 1536
{
  __shared__ __align__(16) float As[GBK][GBM];
  __shared__ __align__(16) float Bs[GBK][GBN];
  const int tid = threadIdx.x;
  const int rm0 = blockIdx.x * GBM;
  const int cn0 = blockIdx.y * GBN;
  const int lr = tid >> 2;
  const int lk = (tid & 3) * 4;
  const int tx = tid & 15;
  const int ty = tid >> 4;
  float acc[4][4] = {};
  const float* Arow = A  + (size_t)(rm0 + lr) * 512 + lk;
  const float* Brow = Bm + (size_t)(cn0 + lr) * 512 + lk;
  for (int k0 = 0; k0 < 512; k0 += GBK){
    const float4 av = *reinterpret_cast<const float4*>(Arow + k0);
    const float4 bv = *reinterpret_cast<const float4*>(Brow + k0);
    __syncthreads();
    As[lk+0][lr]=av.x; As[lk+1][lr]=av.y; As[lk+2][lr]=av.z; As[lk+3][lr]=av.w;
    Bs[lk+0][lr]=bv.x; Bs[lk+1][lr]=bv.y; Bs[lk+2][lr]=bv.z; Bs[lk+3][lr]=bv.w;
    __syncthreads();
    #pragma unroll
    for (int kk = 0; kk < GBK; ++kk){
      const float4 a4 = *reinterpret_cast<const float4*>(&As[kk][tx*4]);
      const float4 b4 = *reinterpret_cast<const float4*>(&Bs[kk][ty*4]);
      const float ar[4] = {a4.x, a4.y, a4.z, a4.w};
      const float br[4] = {b4.x, b4.y, b4.z, b4.w};
      #pragma unroll
      for (int i = 0; i < 4; ++i)
        #pragma unroll
        for (int j = 0; j < 4; ++j)
          acc[i][j] = fmaf(ar[i], br[j], acc[i][j]);
    }
  }
  #pragma unroll
  for (int i = 0; i < 4; ++i){
    float4 st; st.x=acc[i][0]; st.y=acc[i][1]; st.z=acc[i][2]; st.w=acc[i][3];
    *reinterpret_cast<float4*>(&Cm[(size_t)(rm0 + tx*4 + i)*1536 + cn0 + ty*4]) = st;
  }
}

// ------- apply mobius_matvec scaling to P rows -------------------------------
__global__ __launch_bounds__(256) void scale_kernel(
    const float* __restrict__ src,  // nrows x 512 (layer input rows)
    float* __restrict__ P)          // nrows x 1536 (mx, scaled in place)
{
  __shared__ float red[24];
  const int row = blockIdx.x, tid = threadIdx.x;
  const float x0 = src[(size_t)row*512 + tid];
  const float x1 = src[(size_t)row*512 + tid + 256];
  float v[3];
  v[0] = x0*x0 + x1*x1; v[1] = 0.f; v[2] = 0.f;
  block_reduceN<3>(v, red);
  const float xn = sqrtf(v[0] + EPSF);
  const float artx = artanh_f(xn);
  float* Prow = P + (size_t)row*1536;
  float p[6];
  #pragma unroll
  for (int g = 0; g < 3; ++g){
    p[2*g]   = Prow[g*512 + tid];
    p[2*g+1] = Prow[g*512 + tid + 256];
  }
  float m[3];
  #pragma unroll
  for (int g = 0; g < 3; ++g) m[g] = p[2*g]*p[2*g] + p[2*g+1]*p[2*g+1];
  block_reduceN<3>(m, red);
  #pragma unroll
  for (int g = 0; g < 3; ++g){
    const float mn = sqrtf(m[g] + EPSF);
    const float s = tanhf(mn / xn * artx) / mn;
    Prow[g*512 + tid]       = s * p[2*g];
    Prow[g*512 + tid + 256] = s * p[2*g+1];
  }
}

// ---------------- persistent recurrence: 16 groups x 16 blocks ---------------
// per step: A(mv_rz) | bar | B(r-chain + mv_hid) | bar | C(z-chain + finish)
// Chains: 1 wave per batch, full-wave butterfly reduces, zero redundancy.
__global__ __launch_bounds__(256) void recur_kernel(
    const float* __restrict__ Whh,   // (1536,512): [r | hid | z]
    const float* __restrict__ bias,  // (3,512): [b_r, b_h, b_z]
    const float* __restrict__ P,     // CHUNK*Bn x 1536 (scaled x-side)
    const float* __restrict__ hinit, // (B,512) previous h, or nullptr -> zeros
    float* __restrict__ Mrz,         // [2][Bn][1024] double-buffered (sc1)
    float* __restrict__ Mh,          // [Bn][512] (sc1)
    float* __restrict__ outseq,      // (T,B,H)
    float* __restrict__ lastdst,     // (B,H), written at t==Tn-1
    unsigned* __restrict__ flags,    // NGRP * GPB * FSTRIDE, zeroed
    int t0, int nsteps)
{
  __shared__ __align__(16) float h_lds[NBATCH][HPAD];
  __shared__ __align__(16) float v_lds[NBATCH][HPAD];   // rh (phase B)
  __shared__ float stats[NBATCH][4];  // xn_rh, artx_rh, hn2
  const int bid = blockIdx.x, tid = threadIdx.x;
  const int g = bid >> 4, bl = bid & 15;
  unsigned* gflags = flags + (size_t)g * GPB * FSTRIDE;
  unsigned ep = 0;
  const int bb = tid >> 6;        // chain batch (0..3) = wave id
  const int l  = tid & 63;        // lane
  const int b4 = g*NBATCH + bb;   // global batch for chain work

  for (int idx = tid; idx < NBATCH*Hn; idx += 256){
    const int b2 = idx >> 9, j = idx & 511;
    h_lds[b2][j] = hinit ? hinit[(size_t)(g*NBATCH + b2)*Hn + j] : 0.f;
  }
  __syncthreads();

  for (int tt = 0; tt < nsteps; ++tt){
    const int t = t0 + tt;
    const int buf = tt & 1;

    // ---------------- A: mv_rz (64 rows x 4 batches per block) ------------
    {
      const int r_i = tid >> 2, bm = tid & 3;
      const int row_local = bl*64 + r_i;                 // 0..1023
      const int wrow = (row_local < 512) ? row_local : row_local + 512;
      const float4* wp = reinterpret_cast<const float4*>(Whh + (size_t)wrow*Hn);
      const float4* hv = reinterpret_cast<const float4*>(&h_lds[bm][0]);
      float a0=0.f,a1=0.f,a2=0.f,a3=0.f;
      #pragma unroll 8
      for (int k = 0; k < 128; ++k){
        const float4 w = wp[k];
        const float4 x = hv[k];
        a0=fmaf(w.x,x.x,a0); a1=fmaf(w.y,x.y,a1);
        a2=fmaf(w.z,x.z,a2); a3=fmaf(w.w,x.w,a3);
      }
      cstore_f(&Mrz[((size_t)buf*Bn + g*NBATCH + bm)*1024 + row_local],
               (a0+a1)+(a2+a3));
    }
    gbar(gflags, bl, ++ep);

    // ---------------- B: r-chain (1 wave/batch) + mv_hid ------------------
    {
      const float* Mr = Mrz + ((size_t)buf*Bn + b4)*1024;
      const float* pr = P + ((size_t)tt*Bn + b4)*1536;
      float m[8], p[8], bv[8], h[8];
      #pragma unroll
      for (int k = 0; k < 8; ++k){
        const int j = l + 64*k;
        m[k] = cload_f(Mr + j); p[k] = pr[j]; bv[k] = bias[j]; h[k] = h_lds[bb][j];
      }
      float v[3];
      v[0] = 0.f; v[1] = 0.f;
      #pragma unroll
      for (int k = 0; k < 8; ++k){ v[0]=fmaf(h[k],h[k],v[0]); v[1]=fmaf(m[k],m[k],v[1]); }
      red64N<2>(v);
      const float hn2 = v[0];
      const float xn_h = sqrtf(hn2 + EPSF);
      const float artx_h = artanh_f(xn_h);
      const float m2 = v[1];
      const float mn = sqrtf(m2 + EPSF);
      const float s = tanhf(mn/xn_h*artx_h)/mn;
      const float x2 = s*s*m2;
      v[0] = 0.f; v[1] = 0.f;
      #pragma unroll
      for (int k = 0; k < 8; ++k){ v[0]=fmaf(p[k],p[k],v[0]); v[1]=fmaf(s*m[k],p[k],v[1]); }
      red64N<2>(v);
      float na = 1.f + 2.f*v[1] + v[0];
      float nb = 1.f - x2;
      float den = fmaxf(1.f + 2.f*v[1] + x2*v[0], EPSF);
      #pragma unroll
      for (int k = 0; k < 8; ++k) p[k] = (na*s*m[k] + nb*p[k])/den;    // q
      v[0]=0.f; v[1]=0.f; v[2]=0.f;
      #pragma unroll
      for (int k = 0; k < 8; ++k){
        v[0]=fmaf(p[k],p[k],v[0]); v[1]=fmaf(bv[k],bv[k],v[1]); v[2]=fmaf(p[k],bv[k],v[2]);
      }
      red64N<3>(v);
      na = 1.f + 2.f*v[2] + v[1];
      nb = 1.f - v[0];
      den = fmaxf(1.f + 2.f*v[2] + v[0]*v[1], EPSF);
      v[0] = 0.f;
      #pragma unroll
      for (int k = 0; k < 8; ++k){
        m[k] = (na*p[k] + nb*bv[k])/den;                               // w
        v[0] = fmaf(m[k], m[k], v[0]);
      }
      red64N<1>(v);
      const float yn = sqrtf(v[0] + EPSF);
      const float sc = artanh_f(yn)/yn;
      v[0] = 0.f;
      #pragma unroll
      for (int k = 0; k < 8; ++k){
        const float r = 1.f/(1.f + expf(-sc*m[k]));
        m[k] = r*h[k];                                                 // u
        v[0] = fmaf(m[k], m[k], v[0]);
      }
      red64N<1>(v);
      const float u2 = v[0];
      const float wn = sqrtf(u2 + EPSF);
      const float s_rh = tanhf(wn/xn_h*artx_h)/wn;
      #pragma unroll
      for (int k = 0; k < 8; ++k) v_lds[bb][l + 64*k] = s_rh*m[k];     // rh
      if (l == 0){
        const float xnrh = sqrtf(s_rh*s_rh*u2 + EPSF);
        stats[bb][0] = xnrh;
        stats[bb][1] = artanh_f(xnrh);
        stats[bb][2] = hn2;
      }
    }
    __syncthreads();
    if (tid < 128){   // mv_hid: 32 rows x 4 batches
      const int rr = tid >> 2, bm = tid & 3;
      const int wrow = 512 + bl*32 + rr;
      const float4* wp = reinterpret_cast<const float4*>(Whh + (size_t)wrow*Hn);
      const float4* hv = reinterpret_cast<const float4*>(&v_lds[bm][0]);
      float a0=0.f,a1=0.f,a2=0.f,a3=0.f;
      #pragma unroll 8
      for (int k = 0; k < 128; ++k){
        const float4 w = wp[k];
        const float4 x = hv[k];
        a0=fmaf(w.x,x.x,a0); a1=fmaf(w.y,x.y,a1);
        a2=fmaf(w.z,x.z,a2); a3=fmaf(w.w,x.w,a3);
      }
      cstore_f(&Mh[(size_t)(g*NBATCH + bm)*512 + bl*32 + rr], (a0+a1)+(a2+a3));
    }
    gbar(gflags, bl, ++ep);

    // ---------------- C: z-chain + finish (registers end-to-end) ----------
    {
      const float* prow = P + ((size_t)tt*Bn + b4)*1536;
      const float hn2 = stats[bb][2];
      const float xn_h = sqrtf(hn2 + EPSF);
      const float artx_h = artanh_f(xn_h);
      float z[8];
      // ---- z-chain ----
      {
        const float* Mz = Mrz + ((size_t)buf*Bn + b4)*1024 + 512;
        float m[8], p[8], bv[8];
        #pragma unroll
        for (int k = 0; k < 8; ++k){
          const int j = l + 64*k;
          m[k] = cload_f(Mz + j); p[k] = prow[1024 + j]; bv[k] = bias[1024 + j];
        }
        float v[3];
        v[0] = 0.f;
        #pragma unroll
        for (int k = 0; k < 8; ++k) v[0] = fmaf(m[k],m[k],v[0]);
        red64N<1>(v);
        const float m2 = v[0];
        const float mn = sqrtf(m2 + EPSF);
        const float s = tanhf(mn/xn_h*artx_h)/mn;
        const float x2 = s*s*m2;
        v[0]=0.f; v[1]=0.f;
        #pragma unroll
        for (int k = 0; k < 8; ++k){ v[0]=fmaf(p[k],p[k],v[0]); v[1]=fmaf(s*m[k],p[k],v[1]); }
        red64N<2>(v);
        float na = 1.f + 2.f*v[1] + v[0];
        float nb = 1.f - x2;
        float den = fmaxf(1.f + 2.f*v[1] + x2*v[0], EPSF);
        #pragma unroll
        for (int k = 0; k < 8; ++k) p[k] = (na*s*m[k] + nb*p[k])/den;  // q
        v[0]=0.f; v[1]=0.f; v[2]=0.f;
        #pragma unroll
        for (int k = 0; k < 8; ++k){
          v[0]=fmaf(p[k],p[k],v[0]); v[1]=fmaf(bv[k],bv[k],v[1]); v[2]=fmaf(p[k],bv[k],v[2]);
        }
        red64N<3>(v);
        na = 1.f + 2.f*v[2] + v[1];
        nb = 1.f - v[0];
        den = fmaxf(1.f + 2.f*v[2] + v[0]*v[1], EPSF);
        float w2[1] = {0.f};
        #pragma unroll
        for (int k = 0; k < 8; ++k){
          m[k] = (na*p[k] + nb*bv[k])/den;                             // w
          w2[0] = fmaf(m[k], m[k], w2[0]);
        }
        red64N<1>(w2);
        const float yn = sqrtf(w2[0] + EPSF);
        const float sc = artanh_f(yn)/yn;
        #pragma unroll
        for (int k = 0; k < 8; ++k) z[k] = 1.f/(1.f + expf(-sc*m[k]));
      }
      // ---- finish ----
      {
        const float xn_rh = stats[bb][0];
        const float artx_rh = stats[bb][1];
        float m[8], p[8], bv[8], h[8];
        #pragma unroll
        for (int k = 0; k < 8; ++k){
          const int j = l + 64*k;
          m[k] = cload_f(&Mh[(size_t)b4*512 + j]);
          p[k] = prow[512 + j];
          bv[k] = bias[512 + j];
          h[k] = h_lds[bb][j];
        }
        float v[3];
        v[0] = 0.f;
        #pragma unroll
        for (int k = 0; k < 8; ++k) v[0] = fmaf(m[k],m[k],v[0]);
        red64N<1>(v);
        const float m2 = v[0];
        const float mn = sqrtf(m2 + EPSF);
        const float s = tanhf(mn/xn_rh*artx_rh)/mn;
        const float x2 = s*s*m2;
        v[0]=0.f; v[1]=0.f;
        #pragma unroll
        for (int k = 0; k < 8; ++k){ v[0]=fmaf(p[k],p[k],v[0]); v[1]=fmaf(s*m[k],p[k],v[1]); }
        red64N<2>(v);
        float na = 1.f + 2.f*v[1] + v[0];
        float nb = 1.f - x2;
        float den = fmaxf(1.f + 2.f*v[1] + x2*v[0], EPSF);
        #pragma unroll
        for (int k = 0; k < 8; ++k) p[k] = (na*s*m[k] + nb*p[k])/den;  // q
        v[0]=0.f; v[1]=0.f; v[2]=0.f;
        #pragma unroll
        for (int k = 0; k < 8; ++k){
          v[0]=fmaf(p[k],p[k],v[0]); v[1]=fmaf(bv[k],bv[k],v[1]); v[2]=fmaf(p[k],bv[k],v[2]);
        }
        red64N<3>(v);
        na = 1.f + 2.f*v[2] + v[1];
        nb = 1.f - v[0];
        den = fmaxf(1.f + 2.f*v[2] + v[0]*v[1], EPSF);
        #pragma unroll
        for (int k = 0; k < 8; ++k) m[k] = (na*p[k] + nb*bv[k])/den;   // ht
        v[0]=0.f; v[1]=0.f;
        #pragma unroll
        for (int k = 0; k < 8; ++k){ v[0]=fmaf(m[k],m[k],v[0]); v[1]=fmaf(h[k],m[k],v[1]); }
        red64N<2>(v);
        {
          const float y2 = v[0], hht = v[1];
          na = 1.f - 2.f*hht + y2;
          nb = 1.f - hn2;
          den = fmaxf(1.f - 2.f*hht + hn2*y2, EPSF);
          #pragma unroll
          for (int k = 0; k < 8; ++k) p[k] = (na*(-h[k]) + nb*m[k])/den; // delta
        }
        v[0]=0.f; v[1]=0.f; v[2]=0.f;
        #pragma unroll
        for (int k = 0; k < 8; ++k){
          bv[k] = z[k] * p[k];                                          // wz
          v[0] = fmaf(p[k], p[k], v[0]);
          v[1] = fmaf(bv[k], bv[k], v[1]);
          v[2] = fmaf(h[k], bv[k], v[2]);
        }
        red64N<3>(v);
        const float dn  = sqrtf(v[0] + EPSF);
        const float wzn = sqrtf(v[1] + EPSF);
        const float s_pw = tanhf(wzn/dn*artanh_f(dn))/wzn;
        const float y2f = s_pw*s_pw*v[1];
        const float xyf = s_pw*v[2];
        na = 1.f + 2.f*xyf + y2f;
        nb = 1.f - hn2;
        den = fmaxf(1.f + 2.f*xyf + hn2*y2f, EPSF);
        #pragma unroll
        for (int k = 0; k < 8; ++k){
          const int j = l + 64*k;
          const float hn = (na*h[k] + nb*s_pw*bv[k])/den;
          h_lds[bb][j] = hn;
          outseq[((size_t)t*Bn + b4)*512 + j] = hn;
          if (t == Tn-1) lastdst[(size_t)b4*512 + j] = hn;
        }
      }
    }
    __syncthreads();   // protect h_lds before next step's phase A
  }
}

extern "C" void kernel_launch(void* const* d_in, const int* in_sizes, int n_in,
                              void* d_out, int out_size, void* d_ws, size_t ws_size,
                              hipStream_t stream)
{
  const float* inp  = (const float*)d_in[0];   // (T,B,H)
  const float* Wih  = (const float*)d_in[1];   // (L,3H,H)
  const float* Whh  = (const float*)d_in[2];   // (L,3H,H)
  const float* bias = (const float*)d_in[3];   // (L,3,H)
  float* out  = (float*)d_out;                 // (T,B,H)
  float* last = out + (size_t)Tn*Bn*Hn;        // (L,B,H)

  float*    P     = (float*)d_ws;                       // CHUNK*Bn x 1536
  float*    Mrz   = P + (size_t)CHUNK*Bn*1536;          // 2 x Bn x 1024
  float*    Mh    = Mrz + (size_t)2*Bn*1024;            // Bn x 512
  unsigned* flags = (unsigned*)(Mh + (size_t)Bn*512);   // NGRP*GPB*FSTRIDE

  for (int l = 0; l < 2; ++l){
    const float* src   = (l == 0) ? inp : out;
    const float* Wihl  = Wih  + (size_t)l*1536*Hn;
    const float* Whhl  = Whh  + (size_t)l*1536*Hn;
    const float* biasl = bias + (size_t)l*3*Hn;
    for (int c = 0; c < Tn/CHUNK; ++c){
      const int t0 = c*CHUNK;
      const float* srcc = src + (size_t)t0*Bn*Hn;
      dim3 gg(CHUNK*Bn/GBM, 1536/GBN);
      hipLaunchKernelGGL(gemm_tn, gg, dim3(256), 0, stream, srcc, Wihl, P);
      hipLaunchKernelGGL(scale_kernel, dim3(CHUNK*Bn), dim3(256), 0, stream,
                         srcc, P);
      hipMemsetAsync(flags, 0, (size_t)NGRP*GPB*FSTRIDE*sizeof(unsigned), stream);
      const float* hinit = (t0 == 0) ? nullptr
                                     : out + ((size_t)(t0-1))*Bn*Hn;
      hipLaunchKernelGGL(recur_kernel, dim3(NGRP*GPB), dim3(256), 0, stream,
                         Whhl, biasl, P, hinit, Mrz, Mh,
                         out, last + (size_t)l*Bn*Hn, flags, t0, CHUNK);
    }
  }
}

// Round 7
// 11073.594 us; speedup vs baseline: 6.2660x; 1.0099x over previous
//
#include <hip/hip_runtime.h>
#include <math.h>

#define Tn 256
#define Bn 64
#define Hn 512
#define CHUNK 64
#define EPSF 1e-15f
#define NGRP 16     // independent barrier groups
#define GPB 16      // blocks per group
#define NBATCH 4    // batches per group (1 wave per batch in chain phases)
#define HPAD 516    // LDS row stride (floats)
#define FSTRIDE 32  // flag stride (uints) = 128B

typedef float f32x2 __attribute__((ext_vector_type(2)));

__device__ __forceinline__ float artanh_f(float x){
  x = fminf(fmaxf(x, -1.0f + 1e-7f), 1.0f - 1e-7f);
  return 0.5f * (log1pf(x) - log1pf(-x));
}

// full-wave butterfly reduce of N values; every lane ends with the total.
template<int N>
__device__ __forceinline__ void red64N(float* v){
  #pragma unroll
  for (int off = 1; off < 64; off <<= 1){
    #pragma unroll
    for (int n = 0; n < N; ++n) v[n] += __shfl_xor(v[n], off);
  }
}

// ---- LLC (coherence-point) primitives: sc0 sc1, no atomics, pipelined ----
__device__ __forceinline__ void llc_store_f(float* p, float v){
  asm volatile("global_store_dword %0, %1, off sc0 sc1" :: "v"(p), "v"(v) : "memory");
}
// NOTE: result only valid after an explicit s_waitcnt vmcnt(0) + sched_barrier.
__device__ __forceinline__ f32x2 llc_load2(const float* p){
  f32x2 r;
  asm volatile("global_load_dwordx2 %0, %1, off sc0 sc1" : "=v"(r) : "v"(p) : "memory");
  return r;
}
__device__ __forceinline__ void vm_drain(){
  asm volatile("s_waitcnt vmcnt(0)" ::: "memory");
  __builtin_amdgcn_sched_barrier(0);
}

// Group barrier: per-wave vmcnt drain + block barrier, then one sc0sc1 flag
// store by tid0, read-only sc0sc1 polling by GPB lanes. No cache maintenance.
__device__ __forceinline__ void gbar(unsigned* gflags, int bl, unsigned ep){
  asm volatile("s_waitcnt vmcnt(0)" ::: "memory");
  __syncthreads();
  if (threadIdx.x == 0){
    unsigned* fp = gflags + (size_t)bl*FSTRIDE;
    asm volatile("global_store_dword %0, %1, off sc0 sc1" :: "v"(fp), "v"(ep) : "memory");
  }
  if (threadIdx.x < GPB){
    const unsigned* fp = gflags + (size_t)threadIdx.x*FSTRIDE;
    unsigned v;
    do {
      asm volatile("global_load_dword %0, %1, off sc0 sc1\n\ts_waitcnt vmcnt(0)"
                   : "=v"(v) : "v"(fp) : "memory");
    } while (v < ep);
  }
  __syncthreads();
}

template<int N>
__device__ __forceinline__ void block_reduceN(float* v, float* red){
  #pragma unroll
  for (int off = 32; off > 0; off >>= 1){
    #pragma unroll
    for (int n = 0; n < N; ++n) v[n] += __shfl_xor(v[n], off);
  }
  const int tid = threadIdx.x;
  const int w = tid >> 6;
  __syncthreads();
  if ((tid & 63) == 0){
    #pragma unroll
    for (int n = 0; n < N; ++n) red[n*4 + w] = v[n];
  }
  __syncthreads();
  #pragma unroll
  for (int n = 0; n < N; ++n)
    v[n] = red[n*4+0] + red[n*4+1] + red[n*4+2] + red[n*4+3];
}

// ---------------- precompute GEMM: C[r][c] = dot(A[r,:512], B[c,:512]) -------
#define GBM 64
#define GBN 64
#define GBK 16

__global__ __launch_bounds__(256) void gemm_tn(
    const float* __restrict__ A,   // M x 512 row-major (M = CHUNK*Bn)
    const float* __restrict__ Bm,  // 1536 x 512 row-major
    float* __restrict__ Cm)        // M x 1536
{
  __shared__ __align__(16) float As[GBK][GBM];
  __shared__ __align__(16) float Bs[GBK][GBN];
  const int tid = threadIdx.x;
  const int rm0 = blockIdx.x * GBM;
  const int cn0 = blockIdx.y * GBN;
  const int lr = tid >> 2;
  const int lk = (tid & 3) * 4;
  const int tx = tid & 15;
  const int ty = tid >> 4;
  float acc[4][4] = {};
  const float* Arow = A  + (size_t)(rm0 + lr) * 512 + lk;
  const float* Brow = Bm + (size_t)(cn0 + lr) * 512 + lk;
  for (int k0 = 0; k0 < 512; k0 += GBK){
    const float4 av = *reinterpret_cast<const float4*>(Arow + k0);
    const float4 bv = *reinterpret_cast<const float4*>(Brow + k0);
    __syncthreads();
    As[lk+0][lr]=av.x; As[lk+1][lr]=av.y; As[lk+2][lr]=av.z; As[lk+3][lr]=av.w;
    Bs[lk+0][lr]=bv.x; Bs[lk+1][lr]=bv.y; Bs[lk+2][lr]=bv.z; Bs[lk+3][lr]=bv.w;
    __syncthreads();
    #pragma unroll
    for (int kk = 0; kk < GBK; ++kk){
      const float4 a4 = *reinterpret_cast<const float4*>(&As[kk][tx*4]);
      const float4 b4 = *reinterpret_cast<const float4*>(&Bs[kk][ty*4]);
      const float ar[4] = {a4.x, a4.y, a4.z, a4.w};
      const float br[4] = {b4.x, b4.y, b4.z, b4.w};
      #pragma unroll
      for (int i = 0; i < 4; ++i)
        #pragma unroll
        for (int j = 0; j < 4; ++j)
          acc[i][j] = fmaf(ar[i], br[j], acc[i][j]);
    }
  }
  #pragma unroll
  for (int i = 0; i < 4; ++i){
    float4 st; st.x=acc[i][0]; st.y=acc[i][1]; st.z=acc[i][2]; st.w=acc[i][3];
    *reinterpret_cast<float4*>(&Cm[(size_t)(rm0 + tx*4 + i)*1536 + cn0 + ty*4]) = st;
  }
}

// ------- apply mobius_matvec scaling to P rows -------------------------------
__global__ __launch_bounds__(256) void scale_kernel(
    const float* __restrict__ src,  // nrows x 512 (layer input rows)
    float* __restrict__ P)          // nrows x 1536 (mx, scaled in place)
{
  __shared__ float red[24];
  const int row = blockIdx.x, tid = threadIdx.x;
  const float x0 = src[(size_t)row*512 + tid];
  const float x1 = src[(size_t)row*512 + tid + 256];
  float v[3];
  v[0] = x0*x0 + x1*x1; v[1] = 0.f; v[2] = 0.f;
  block_reduceN<3>(v, red);
  const float xn = sqrtf(v[0] + EPSF);
  const float artx = artanh_f(xn);
  float* Prow = P + (size_t)row*1536;
  float p[6];
  #pragma unroll
  for (int g = 0; g < 3; ++g){
    p[2*g]   = Prow[g*512 + tid];
    p[2*g+1] = Prow[g*512 + tid + 256];
  }
  float m[3];
  #pragma unroll
  for (int g = 0; g < 3; ++g) m[g] = p[2*g]*p[2*g] + p[2*g+1]*p[2*g+1];
  block_reduceN<3>(m, red);
  #pragma unroll
  for (int g = 0; g < 3; ++g){
    const float mn = sqrtf(m[g] + EPSF);
    const float s = tanhf(mn / xn * artx) / mn;
    Prow[g*512 + tid]       = s * p[2*g];
    Prow[g*512 + tid + 256] = s * p[2*g+1];
  }
}

// ---------------- persistent recurrence: 16 groups x 16 blocks ---------------
// step: A(mv_rz) | bar | B1(r-chains) B2(mv_hid || z-chains) | bar | C(finish)
// lane-major mapping j = 2*l + 128*e for all chain vectors.
__global__ __launch_bounds__(256) void recur_kernel(
    const float* __restrict__ Whh,   // (1536,512): [r | hid | z]
    const float* __restrict__ bias,  // (3,512): [b_r, b_h, b_z]
    const float* __restrict__ P,     // CHUNK*Bn x 1536 (scaled x-side)
    const float* __restrict__ hinit, // (B,512) previous h, or nullptr -> zeros
    float* __restrict__ Mrz,         // [2][Bn][1024] double-buffered (LLC)
    float* __restrict__ Mh,          // [Bn][512] (LLC)
    float* __restrict__ outseq,      // (T,B,H)
    float* __restrict__ lastdst,     // (B,H), written at t==Tn-1
    unsigned* __restrict__ flags,    // NGRP * GPB * FSTRIDE, zeroed
    int t0, int nsteps)
{
  __shared__ __align__(16) float h_lds[NBATCH][HPAD];
  __shared__ __align__(16) float v_lds[NBATCH][HPAD];   // rh
  __shared__ __align__(16) float z_lds[NBATCH][HPAD];   // z gate
  __shared__ float stats[NBATCH][4];  // xn_rh, artx_rh, hn2
  const int bid = blockIdx.x, tid = threadIdx.x;
  const int g = bid >> 4, bl = bid & 15;
  unsigned* gflags = flags + (size_t)g * GPB * FSTRIDE;
  unsigned ep = 0;
  const int bb = tid >> 6;        // wave id = chain batch (0..3)
  const int l  = tid & 63;        // lane
  const int b4 = g*NBATCH + bb;   // global batch for chain work

  for (int idx = tid; idx < NBATCH*Hn; idx += 256){
    const int b2 = idx >> 9, j = idx & 511;
    h_lds[b2][j] = hinit ? hinit[(size_t)(g*NBATCH + b2)*Hn + j] : 0.f;
  }
  __syncthreads();

  for (int tt = 0; tt < nsteps; ++tt){
    const int t = t0 + tt;
    const int buf = tt & 1;

    // ---------------- A: mv_rz (64 rows x 4 batches per block) ------------
    {
      const int r_i = tid >> 2, bm = tid & 3;
      const int row_local = bl*64 + r_i;                 // 0..1023
      const int wrow = (row_local < 512) ? row_local : row_local + 512;
      const float4* wp = reinterpret_cast<const float4*>(Whh + (size_t)wrow*Hn);
      const float4* hv = reinterpret_cast<const float4*>(&h_lds[bm][0]);
      float a0=0.f,a1=0.f,a2=0.f,a3=0.f;
      #pragma unroll 8
      for (int k = 0; k < 128; ++k){
        const float4 w = wp[k];
        const float4 x = hv[k];
        a0=fmaf(w.x,x.x,a0); a1=fmaf(w.y,x.y,a1);
        a2=fmaf(w.z,x.z,a2); a3=fmaf(w.w,x.w,a3);
      }
      llc_store_f(&Mrz[((size_t)buf*Bn + g*NBATCH + bm)*1024 + row_local],
                  (a0+a1)+(a2+a3));
    }
    gbar(gflags, bl, ++ep);

    // ---------------- B1: r-chain, 1 wave per batch ------------------------
    {
      const float* Mr = Mrz + ((size_t)buf*Bn + b4)*1024;
      f32x2 mr[4], p2[4], bv2[4], h2[4];
      #pragma unroll
      for (int e = 0; e < 4; ++e) mr[e] = llc_load2(Mr + 2*l + 128*e);
      const float* prow = P + ((size_t)tt*Bn + b4)*1536;
      #pragma unroll
      for (int e = 0; e < 4; ++e){
        p2[e]  = *(const f32x2*)(prow + 2*l + 128*e);
        bv2[e] = *(const f32x2*)(bias + 2*l + 128*e);
        h2[e]  = *(const f32x2*)(&h_lds[bb][2*l + 128*e]);
      }
      vm_drain();
      float m[8], p[8], bv[8], h[8];
      #pragma unroll
      for (int e = 0; e < 4; ++e){
        m[2*e]=mr[e][0];  m[2*e+1]=mr[e][1];
        p[2*e]=p2[e][0];  p[2*e+1]=p2[e][1];
        bv[2*e]=bv2[e][0];bv[2*e+1]=bv2[e][1];
        h[2*e]=h2[e][0];  h[2*e+1]=h2[e][1];
      }
      float v[3];
      v[0]=0.f; v[1]=0.f;
      #pragma unroll
      for (int k = 0; k < 8; ++k){ v[0]=fmaf(h[k],h[k],v[0]); v[1]=fmaf(m[k],m[k],v[1]); }
      red64N<2>(v);
      const float hn2 = v[0];
      const float xn_h = sqrtf(hn2 + EPSF);
      const float artx_h = artanh_f(xn_h);
      const float m2 = v[1];
      const float mn = sqrtf(m2 + EPSF);
      const float s = tanhf(mn/xn_h*artx_h)/mn;
      const float x2 = s*s*m2;
      v[0]=0.f; v[1]=0.f;
      #pragma unroll
      for (int k = 0; k < 8; ++k){ v[0]=fmaf(p[k],p[k],v[0]); v[1]=fmaf(s*m[k],p[k],v[1]); }
      red64N<2>(v);
      float na = 1.f + 2.f*v[1] + v[0];
      float nb = 1.f - x2;
      float den = fmaxf(1.f + 2.f*v[1] + x2*v[0], EPSF);
      #pragma unroll
      for (int k = 0; k < 8; ++k) p[k] = (na*s*m[k] + nb*p[k])/den;    // q
      v[0]=0.f; v[1]=0.f; v[2]=0.f;
      #pragma unroll
      for (int k = 0; k < 8; ++k){
        v[0]=fmaf(p[k],p[k],v[0]); v[1]=fmaf(bv[k],bv[k],v[1]); v[2]=fmaf(p[k],bv[k],v[2]);
      }
      red64N<3>(v);
      na = 1.f + 2.f*v[2] + v[1];
      nb = 1.f - v[0];
      den = fmaxf(1.f + 2.f*v[2] + v[0]*v[1], EPSF);
      v[0] = 0.f;
      #pragma unroll
      for (int k = 0; k < 8; ++k){
        m[k] = (na*p[k] + nb*bv[k])/den;                               // w
        v[0] = fmaf(m[k], m[k], v[0]);
      }
      red64N<1>(v);
      const float yn = sqrtf(v[0] + EPSF);
      const float sc = artanh_f(yn)/yn;
      v[0] = 0.f;
      #pragma unroll
      for (int k = 0; k < 8; ++k){
        const float r = 1.f/(1.f + expf(-sc*m[k]));
        m[k] = r*h[k];                                                 // u
        v[0] = fmaf(m[k], m[k], v[0]);
      }
      red64N<1>(v);
      const float u2 = v[0];
      const float wn = sqrtf(u2 + EPSF);
      const float s_rh = tanhf(wn/xn_h*artx_h)/wn;
      #pragma unroll
      for (int e = 0; e < 4; ++e){
        f32x2 rr; rr[0]=s_rh*m[2*e]; rr[1]=s_rh*m[2*e+1];
        *(f32x2*)(&v_lds[bb][2*l + 128*e]) = rr;
      }
      if (l == 0){
        const float xnrh = sqrtf(s_rh*s_rh*u2 + EPSF);
        stats[bb][0] = xnrh;
        stats[bb][1] = artanh_f(xnrh);
        stats[bb][2] = hn2;
      }
    }
    __syncthreads();

    // ---------------- B2: mv_hid (waves 0-1)  ||  z-chains (waves 2-3) ----
    if (tid < 128){
      const int rr = tid >> 2, bm = tid & 3;       // 32 rows x 4 batches
      const int wrow = 512 + bl*32 + rr;
      const float4* wp = reinterpret_cast<const float4*>(Whh + (size_t)wrow*Hn);
      const float4* hv = reinterpret_cast<const float4*>(&v_lds[bm][0]);
      float a0=0.f,a1=0.f,a2=0.f,a3=0.f;
      #pragma unroll 8
      for (int k = 0; k < 128; ++k){
        const float4 w = wp[k];
        const float4 x = hv[k];
        a0=fmaf(w.x,x.x,a0); a1=fmaf(w.y,x.y,a1);
        a2=fmaf(w.z,x.z,a2); a3=fmaf(w.w,x.w,a3);
      }
      llc_store_f(&Mh[(size_t)(g*NBATCH + bm)*512 + bl*32 + rr], (a0+a1)+(a2+a3));
    } else {
      const int zw = (tid >> 6) - 2;               // 0 or 1
      f32x2 mz[2][4];
      #pragma unroll
      for (int i = 0; i < 2; ++i){
        const int bz = g*NBATCH + zw*2 + i;
        const float* Mz = Mrz + ((size_t)buf*Bn + bz)*1024 + 512;
        #pragma unroll
        for (int e = 0; e < 4; ++e) mz[i][e] = llc_load2(Mz + 2*l + 128*e);
      }
      vm_drain();
      #pragma unroll
      for (int i = 0; i < 2; ++i){
        const int bzl = zw*2 + i;
        const int bz = g*NBATCH + bzl;
        const float* prow = P + ((size_t)tt*Bn + bz)*1536;
        float m[8], p[8], bv[8];
        #pragma unroll
        for (int e = 0; e < 4; ++e){
          m[2*e]=mz[i][e][0]; m[2*e+1]=mz[i][e][1];
          const f32x2 pp = *(const f32x2*)(prow + 1024 + 2*l + 128*e);
          p[2*e]=pp[0]; p[2*e+1]=pp[1];
          const f32x2 bb2 = *(const f32x2*)(bias + 1024 + 2*l + 128*e);
          bv[2*e]=bb2[0]; bv[2*e+1]=bb2[1];
        }
        const float hn2 = stats[bzl][2];
        const float xn_h = sqrtf(hn2 + EPSF);
        const float artx_h = artanh_f(xn_h);
        float v[3];
        v[0] = 0.f;
        #pragma unroll
        for (int k = 0; k < 8; ++k) v[0] = fmaf(m[k],m[k],v[0]);
        red64N<1>(v);
        const float m2 = v[0];
        const float mn = sqrtf(m2 + EPSF);
        const float s = tanhf(mn/xn_h*artx_h)/mn;
        const float x2 = s*s*m2;
        v[0]=0.f; v[1]=0.f;
        #pragma unroll
        for (int k = 0; k < 8; ++k){ v[0]=fmaf(p[k],p[k],v[0]); v[1]=fmaf(s*m[k],p[k],v[1]); }
        red64N<2>(v);
        float na = 1.f + 2.f*v[1] + v[0];
        float nb = 1.f - x2;
        float den = fmaxf(1.f + 2.f*v[1] + x2*v[0], EPSF);
        #pragma unroll
        for (int k = 0; k < 8; ++k) p[k] = (na*s*m[k] + nb*p[k])/den;  // q
        v[0]=0.f; v[1]=0.f; v[2]=0.f;
        #pragma unroll
        for (int k = 0; k < 8; ++k){
          v[0]=fmaf(p[k],p[k],v[0]); v[1]=fmaf(bv[k],bv[k],v[1]); v[2]=fmaf(p[k],bv[k],v[2]);
        }
        red64N<3>(v);
        na = 1.f + 2.f*v[2] + v[1];
        nb = 1.f - v[0];
        den = fmaxf(1.f + 2.f*v[2] + v[0]*v[1], EPSF);
        float w2[1] = {0.f};
        #pragma unroll
        for (int k = 0; k < 8; ++k){
          m[k] = (na*p[k] + nb*bv[k])/den;                             // w
          w2[0] = fmaf(m[k], m[k], w2[0]);
        }
        red64N<1>(w2);
        const float yn = sqrtf(w2[0] + EPSF);
        const float sc = artanh_f(yn)/yn;
        #pragma unroll
        for (int e = 0; e < 4; ++e){
          f32x2 zz;
          zz[0] = 1.f/(1.f + expf(-sc*m[2*e]));
          zz[1] = 1.f/(1.f + expf(-sc*m[2*e+1]));
          *(f32x2*)(&z_lds[bzl][2*l + 128*e]) = zz;
        }
      }
    }
    gbar(gflags, bl, ++ep);

    // ---------------- C: finish (1 wave per batch) -------------------------
    {
      f32x2 mh2[4];
      #pragma unroll
      for (int e = 0; e < 4; ++e)
        mh2[e] = llc_load2(Mh + (size_t)b4*512 + 2*l + 128*e);
      const float* prow = P + ((size_t)tt*Bn + b4)*1536;
      f32x2 p2[4], bv2[4], h2[4], z2[4];
      #pragma unroll
      for (int e = 0; e < 4; ++e){
        p2[e]  = *(const f32x2*)(prow + 512 + 2*l + 128*e);
        bv2[e] = *(const f32x2*)(bias + 512 + 2*l + 128*e);
        h2[e]  = *(const f32x2*)(&h_lds[bb][2*l + 128*e]);
        z2[e]  = *(const f32x2*)(&z_lds[bb][2*l + 128*e]);
      }
      vm_drain();
      float m[8], p[8], bv[8], h[8], z[8];
      #pragma unroll
      for (int e = 0; e < 4; ++e){
        m[2*e]=mh2[e][0]; m[2*e+1]=mh2[e][1];
        p[2*e]=p2[e][0];  p[2*e+1]=p2[e][1];
        bv[2*e]=bv2[e][0];bv[2*e+1]=bv2[e][1];
        h[2*e]=h2[e][0];  h[2*e+1]=h2[e][1];
        z[2*e]=z2[e][0];  z[2*e+1]=z2[e][1];
      }
      const float hn2 = stats[bb][2];
      const float xn_rh = stats[bb][0];
      const float artx_rh = stats[bb][1];
      float v[3];
      v[0] = 0.f;
      #pragma unroll
      for (int k = 0; k < 8; ++k) v[0] = fmaf(m[k],m[k],v[0]);
      red64N<1>(v);
      const float m2 = v[0];
      const float mn = sqrtf(m2 + EPSF);
      const float s = tanhf(mn/xn_rh*artx_rh)/mn;
      const float x2 = s*s*m2;
      v[0]=0.f; v[1]=0.f;
      #pragma unroll
      for (int k = 0; k < 8; ++k){ v[0]=fmaf(p[k],p[k],v[0]); v[1]=fmaf(s*m[k],p[k],v[1]); }
      red64N<2>(v);
      float na = 1.f + 2.f*v[1] + v[0];
      float nb = 1.f - x2;
      float den = fmaxf(1.f + 2.f*v[1] + x2*v[0], EPSF);
      #pragma unroll
      for (int k = 0; k < 8; ++k) p[k] = (na*s*m[k] + nb*p[k])/den;    // q
      v[0]=0.f; v[1]=0.f; v[2]=0.f;
      #pragma unroll
      for (int k = 0; k < 8; ++k){
        v[0]=fmaf(p[k],p[k],v[0]); v[1]=fmaf(bv[k],bv[k],v[1]); v[2]=fmaf(p[k],bv[k],v[2]);
      }
      red64N<3>(v);
      na = 1.f + 2.f*v[2] + v[1];
      nb = 1.f - v[0];
      den = fmaxf(1.f + 2.f*v[2] + v[0]*v[1], EPSF);
      #pragma unroll
      for (int k = 0; k < 8; ++k) m[k] = (na*p[k] + nb*bv[k])/den;     // ht
      v[0]=0.f; v[1]=0.f;
      #pragma unroll
      for (int k = 0; k < 8; ++k){ v[0]=fmaf(m[k],m[k],v[0]); v[1]=fmaf(h[k],m[k],v[1]); }
      red64N<2>(v);
      {
        const float y2 = v[0], hht = v[1];
        na = 1.f - 2.f*hht + y2;
        nb = 1.f - hn2;
        den = fmaxf(1.f - 2.f*hht + hn2*y2, EPSF);
        #pragma unroll
        for (int k = 0; k < 8; ++k) p[k] = (na*(-h[k]) + nb*m[k])/den; // delta
      }
      v[0]=0.f; v[1]=0.f; v[2]=0.f;
      #pragma unroll
      for (int k = 0; k < 8; ++k){
        bv[k] = z[k] * p[k];                                           // wz
        v[0] = fmaf(p[k], p[k], v[0]);
        v[1] = fmaf(bv[k], bv[k], v[1]);
        v[2] = fmaf(h[k], bv[k], v[2]);
      }
      red64N<3>(v);
      const float dn  = sqrtf(v[0] + EPSF);
      const float wzn = sqrtf(v[1] + EPSF);
      const float s_pw = tanhf(wzn/dn*artanh_f(dn))/wzn;
      const float y2f = s_pw*s_pw*v[1];
      const float xyf = s_pw*v[2];
      na = 1.f + 2.f*xyf + y2f;
      nb = 1.f - hn2;
      den = fmaxf(1.f + 2.f*xyf + hn2*y2f, EPSF);
      float* outp = outseq + ((size_t)t*Bn + b4)*512;
      float* lastp = lastdst + (size_t)b4*512;
      #pragma unroll
      for (int e = 0; e < 4; ++e){
        f32x2 hv;
        hv[0] = (na*h[2*e]   + nb*s_pw*bv[2*e])/den;
        hv[1] = (na*h[2*e+1] + nb*s_pw*bv[2*e+1])/den;
        *(f32x2*)(&h_lds[bb][2*l + 128*e]) = hv;
        *(f32x2*)(outp + 2*l + 128*e) = hv;
        if (t == Tn-1) *(f32x2*)(lastp + 2*l + 128*e) = hv;
      }
    }
    __syncthreads();   // protect h_lds before next step's phase A
  }
}

extern "C" void kernel_launch(void* const* d_in, const int* in_sizes, int n_in,
                              void* d_out, int out_size, void* d_ws, size_t ws_size,
                              hipStream_t stream)
{
  const float* inp  = (const float*)d_in[0];   // (T,B,H)
  const float* Wih  = (const float*)d_in[1];   // (L,3H,H)
  const float* Whh  = (const float*)d_in[2];   // (L,3H,H)
  const float* bias = (const float*)d_in[3];   // (L,3,H)
  float* out  = (float*)d_out;                 // (T,B,H)
  float* last = out + (size_t)Tn*Bn*Hn;        // (L,B,H)

  float*    P     = (float*)d_ws;                       // CHUNK*Bn x 1536
  float*    Mrz   = P + (size_t)CHUNK*Bn*1536;          // 2 x Bn x 1024
  float*    Mh    = Mrz + (size_t)2*Bn*1024;            // Bn x 512
  unsigned* flags = (unsigned*)(Mh + (size_t)Bn*512);   // NGRP*GPB*FSTRIDE

  for (int l = 0; l < 2; ++l){
    const float* src   = (l == 0) ? inp : out;
    const float* Wihl  = Wih  + (size_t)l*1536*Hn;
    const float* Whhl  = Whh  + (size_t)l*1536*Hn;
    const float* biasl = bias + (size_t)l*3*Hn;
    for (int c = 0; c < Tn/CHUNK; ++c){
      const int t0 = c*CHUNK;
      const float* srcc = src + (size_t)t0*Bn*Hn;
      dim3 gg(CHUNK*Bn/GBM, 1536/GBN);
      hipLaunchKernelGGL(gemm_tn, gg, dim3(256), 0, stream, srcc, Wihl, P);
      hipLaunchKernelGGL(scale_kernel, dim3(CHUNK*Bn), dim3(256), 0, stream,
                         srcc, P);
      hipMemsetAsync(flags, 0, (size_t)NGRP*GPB*FSTRIDE*sizeof(unsigned), stream);
      const float* hinit = (t0 == 0) ? nullptr
                                     : out + ((size_t)(t0-1))*Bn*Hn;
      hipLaunchKernelGGL(recur_kernel, dim3(NGRP*GPB), dim3(256), 0, stream,
                         Whhl, biasl, P, hinit, Mrz, Mh,
                         out, last + (size_t)l*Bn*Hn, flags, t0, CHUNK);
    }
  }
}